// Round 1
// baseline (10214.745 us; speedup 1.0000x reference)
//
#include <hip/hip_runtime.h>

#define B_ 2
#define S_ 2048
#define D_ 2048
#define L_ 3
#define H_ 16
#define DH_ 128
#define BLK_ 16
#define NA_ 64
#define Q_ 1024
#define KV_ 3072
#define VOCAB_ 32000
#define MASK_ID_ 31999
#define NTOK_ (B_*Q_)          // 2048
#define VTILES_ (VOCAB_/64)    // 500

// ---------------- meta: draft ids / positions / labels ----------------
__global__ void k_meta(const int* __restrict__ ids, const int* __restrict__ anchors,
                       int* __restrict__ dids, int* __restrict__ dpos, int* __restrict__ labels) {
  int t = blockIdx.x * 256 + threadIdx.x;
  if (t >= NTOK_) return;
  int b = t >> 10, qi = t & 1023;
  int a = qi >> 4, off = qi & 15;
  int ap = anchors[b * NA_ + a];
  dpos[t] = ap + off;
  dids[t] = (off == 0) ? ids[b * S_ + ap] : MASK_ID_;
  labels[t] = (off == 0) ? -100 : ids[b * S_ + ap + off];
}

// ---------------- embedding gather into x_kv draft rows ----------------
__global__ void k_gather(const float* __restrict__ table, const int* __restrict__ dids,
                         float* __restrict__ x_kv) {
  int row = blockIdx.x;                 // 0..NTOK_
  int b = row >> 10, qi = row & 1023;
  const float4* src = (const float4*)(table + (size_t)dids[row] * D_);
  float4* dst = (float4*)(x_kv + ((size_t)b * KV_ + S_ + qi) * D_);
  for (int i = threadIdx.x; i < D_ / 4; i += 256) dst[i] = src[i];
}

// ---------------- generic f32 NT SGEMM: C[M,N] = A[M,K] * Bw[N,K]^T ----------------
// AMODE 0: A addr = r*lda + (r>>adivlog)*abump + k
// AMODE 1: ctx-cat gather: A addr = (k>>11)*(B_*S_*D_) + r*D_ + (k&2047)
// EPI 0: store C (row addr = r*N + (r>>cdivlog)*cbump)
// EPI 1: per-row softmax partials over the 64-col tile (LM head)
template <int AMODE, int EPI>
__global__ __launch_bounds__(256) void k_sgemm_nt(
    const float* __restrict__ A, const float* __restrict__ Bw, float* __restrict__ C,
    int N, int K, int lda, int adivlog, long long abump, int cdivlog, long long cbump,
    const int* __restrict__ labels,
    float* __restrict__ pm, float* __restrict__ ps, int* __restrict__ pbi,
    float* __restrict__ plab) {
  __shared__ __align__(16) float As[16][64];
  __shared__ __align__(16) float Bs[16][64];
  __shared__ float extra[128];
  int nt = N >> 6;
  int bx = blockIdx.x % nt, by = blockIdx.x / nt;
  int rowbase = by << 6, colbase = bx << 6;
  int tid = threadIdx.x;
  int tx = tid & 15, ty = tid >> 4;
  int lr = tid >> 2;            // 0..63
  int lk = (tid & 3) << 2;      // 0,4,8,12
  float acc[4][4] = {};
  for (int kt = 0; kt < K; kt += 16) {
    {
      int kg = kt + lk;
      const float* ap;
      if (AMODE == 1) {
        int l = kg >> 11, dd = kg & 2047;
        ap = A + (size_t)l * ((size_t)B_ * S_ * D_) + (size_t)(rowbase + lr) * D_ + dd;
      } else {
        int r = rowbase + lr;
        ap = A + (size_t)r * lda + (size_t)(r >> adivlog) * abump + kg;
      }
      float4 v = *(const float4*)ap;
      As[lk + 0][lr] = v.x; As[lk + 1][lr] = v.y; As[lk + 2][lr] = v.z; As[lk + 3][lr] = v.w;
      const float* bp = Bw + (size_t)(colbase + lr) * K + kg;
      float4 w = *(const float4*)bp;
      Bs[lk + 0][lr] = w.x; Bs[lk + 1][lr] = w.y; Bs[lk + 2][lr] = w.z; Bs[lk + 3][lr] = w.w;
    }
    __syncthreads();
#pragma unroll
    for (int kk = 0; kk < 16; ++kk) {
      float4 av = *(const float4*)&As[kk][ty << 2];
      float4 bv = *(const float4*)&Bs[kk][tx << 2];
      float a[4] = {av.x, av.y, av.z, av.w};
      float bb[4] = {bv.x, bv.y, bv.z, bv.w};
#pragma unroll
      for (int i = 0; i < 4; ++i)
#pragma unroll
        for (int j = 0; j < 4; ++j) acc[i][j] = fmaf(a[i], bb[j], acc[i][j]);
    }
    __syncthreads();
  }
  if (EPI == 0) {
#pragma unroll
    for (int i = 0; i < 4; ++i) {
      int grow = rowbase + (ty << 2) + i;
      size_t base = (size_t)grow * N + (size_t)(grow >> cdivlog) * cbump + colbase + (tx << 2);
      float4 o = make_float4(acc[i][0], acc[i][1], acc[i][2], acc[i][3]);
      *(float4*)(C + base) = o;
    }
  } else {
    float* redf = &As[0][0];
    int* redi = (int*)&Bs[0][0];
    if (tid < 64) extra[64 + tid] = -3.0e38f;   // label logit slot
    // local max / argmax over this thread's 4 cols
#pragma unroll
    for (int i = 0; i < 4; ++i) {
      float best = acc[i][0]; int bidx = 0;
#pragma unroll
      for (int j = 1; j < 4; ++j) if (acc[i][j] > best) { best = acc[i][j]; bidx = j; }
      redf[((ty << 2) + i) * 16 + tx] = best;
      redi[((ty << 2) + i) * 16 + tx] = colbase + (tx << 2) + bidx;
    }
    __syncthreads();
    int rbi = 0;
    if (tid < 64) {
      int row = tid;
      float m = redf[row * 16]; int bi = redi[row * 16];
      for (int x = 1; x < 16; ++x) {
        float v = redf[row * 16 + x];
        if (v > m) { m = v; bi = redi[row * 16 + x]; }
      }
      extra[row] = m; rbi = bi;
    }
    __syncthreads();
    // sumexp with row max; label-logit capture
    float ls[4];
#pragma unroll
    for (int i = 0; i < 4; ++i) {
      int row = (ty << 2) + i;
      int grow = rowbase + row;
      float m = extra[row];
      float s = 0.f;
#pragma unroll
      for (int j = 0; j < 4; ++j) s += __expf(acc[i][j] - m);
      ls[i] = s;
      int lab = labels[grow];
      int rel = lab - (colbase + (tx << 2));
      if (rel >= 0 && rel < 4) extra[64 + row] = acc[i][rel];
      redf[row * 16 + tx] = s;
    }
    __syncthreads();
    if (tid < 64) {
      int row = tid, grow = rowbase + row;
      float s = 0.f;
      for (int x = 0; x < 16; ++x) s += redf[row * 16 + x];
      size_t pidx = (size_t)grow * VTILES_ + bx;
      pm[pidx] = extra[row];
      ps[pidx] = s;
      pbi[pidx] = rbi;
      plab[pidx] = extra[64 + row];
    }
    (void)ls;
  }
}

// ---------------- RoPE in-place. mode 0: q rows (B*Q). mode 1: k rows (B*KV) ----------------
__global__ void k_rope(float* __restrict__ x, const int* __restrict__ dpos, int mode) {
  int idx = blockIdx.x * 256 + threadIdx.x;   // (row, h, j)
  int j = idx & 63;
  int h = (idx >> 6) & 15;
  int row = idx >> 10;
  int pos;
  if (mode == 0) {
    if (row >= NTOK_) return;
    pos = dpos[row];
  } else {
    if (row >= B_ * KV_) return;
    int b = row / KV_, kvi = row % KV_;
    pos = (kvi < S_) ? kvi : dpos[b * Q_ + (kvi - S_)];
  }
  float inv = expf(-(float)j * (9.210340371976184f / 64.f));   // 10000^(-j/64)
  float ang = (float)pos * inv;
  float c = cosf(ang), s = sinf(ang);
  float* p = x + (size_t)row * D_ + h * DH_ + j;
  float x1 = p[0], x2 = p[64];
  p[0] = x1 * c - x2 * s;
  p[64] = x2 * c + x1 * s;
}

// ---------------- attention: one wave per (b,h,query), online softmax ----------------
__global__ __launch_bounds__(256) void k_attn(
    const float* __restrict__ qb, const float* __restrict__ kb, const float* __restrict__ vb,
    const int* __restrict__ anchors, float* __restrict__ ob) {
  int wid = (blockIdx.x << 2) + (threadIdx.x >> 6);  // 0..B*H*Q
  int lane = threadIdx.x & 63;
  int qi = wid & (Q_ - 1);
  int h = (wid >> 10) & (H_ - 1);
  int b = wid >> 14;
  int apos = anchors[b * NA_ + (qi >> 4)];
  const float* qrow = qb + ((size_t)(b * Q_ + qi)) * D_ + h * DH_;
  float2 qv = *(const float2*)(qrow + 2 * lane);
  const float scl = 0.08838834764831845f;  // 1/sqrt(128)
  qv.x *= scl; qv.y *= scl;
  const float* kbase = kb + ((size_t)b * KV_) * D_ + h * DH_ + 2 * lane;
  const float* vbase = vb + ((size_t)b * KV_) * D_ + h * DH_ + 2 * lane;
  float m = -3.0e38f, l = 0.f, a0 = 0.f, a1 = 0.f;
  int dstart = S_ + (qi >> 4) * BLK_;
  int nkeys = apos + BLK_;
  for (int k = 0; k < nkeys; ++k) {
    int kk = (k < apos) ? k : (dstart + (k - apos));
    float2 kv2 = *(const float2*)(kbase + (size_t)kk * D_);
    float2 vv2 = *(const float2*)(vbase + (size_t)kk * D_);
    float part = qv.x * kv2.x + qv.y * kv2.y;
#pragma unroll
    for (int off = 32; off; off >>= 1) part += __shfl_xor(part, off);
    float mn = fmaxf(m, part);
    float corr = __expf(m - mn);
    float p = __expf(part - mn);
    l = l * corr + p;
    a0 = a0 * corr + p * vv2.x;
    a1 = a1 * corr + p * vv2.y;
    m = mn;
  }
  float invl = 1.f / l;
  float* orow = ob + ((size_t)(b * Q_ + qi)) * D_ + h * DH_ + 2 * lane;
  orow[0] = a0 * invl;
  orow[1] = a1 * invl;
}

// ---------------- residual + RMSNorm ----------------
__global__ void k_rmsnorm(const float* __restrict__ x_kv, const float* __restrict__ proj,
                          const float* __restrict__ nw, float* __restrict__ outp) {
  int row = blockIdx.x;   // 0..NTOK_
  int b = row >> 10, qi = row & 1023;
  const float* emb = x_kv + ((size_t)b * KV_ + S_ + qi) * D_;
  const float* pr = proj + (size_t)row * D_;
  __shared__ float red[256];
  float h[8];
  float ssum = 0.f;
#pragma unroll
  for (int i = 0; i < 8; ++i) {
    int d = threadIdx.x + i * 256;
    h[i] = emb[d] + pr[d];
    ssum += h[i] * h[i];
  }
  red[threadIdx.x] = ssum;
  __syncthreads();
  for (int s = 128; s; s >>= 1) {
    if (threadIdx.x < s) red[threadIdx.x] += red[threadIdx.x + s];
    __syncthreads();
  }
  float scale = rsqrtf(red[0] / (float)D_ + 1e-6f);
#pragma unroll
  for (int i = 0; i < 8; ++i) {
    int d = threadIdx.x + i * 256;
    outp[(size_t)row * D_ + d] = h[i] * scale * nw[d];
  }
}

// ---------------- combine LM-head partials -> per-token stats ----------------
__global__ void k_combine(const float* __restrict__ pm, const float* __restrict__ ps,
                          const int* __restrict__ pbi, const float* __restrict__ plab,
                          const int* __restrict__ labels, float* __restrict__ ts) {
  int t = blockIdx.x * 256 + threadIdx.x;
  if (t >= NTOK_) return;
  const float* pmr = pm + (size_t)t * VTILES_;
  const float* psr = ps + (size_t)t * VTILES_;
  const int* pbir = pbi + (size_t)t * VTILES_;
  const float* plabr = plab + (size_t)t * VTILES_;
  float M = -3.0e38f; int bi = 0;
  for (int x = 0; x < VTILES_; ++x) {
    float v = pmr[x];
    if (v > M) { M = v; bi = pbir[x]; }
  }
  float ssum = 0.f, labl = -3.0e38f;
  for (int x = 0; x < VTILES_; ++x) {
    ssum += psr[x] * __expf(pmr[x] - M);
    labl = fmaxf(labl, plabr[x]);
  }
  float lse = M + logf(ssum);
  int lab = labels[t];
  int off = t & 15;
  float valid = (lab != -100) ? 1.f : 0.f;
  float w = (off == 0) ? 0.f : __expf(-(float)(off - 1) / 7.0f);
  w *= valid;
  float nll = (lab != -100) ? (lse - labl) : 0.f;
  float correct = (valid > 0.f && bi == lab) ? 1.f : 0.f;
  ts[t * 4 + 0] = nll * w;
  ts[t * 4 + 1] = w;
  ts[t * 4 + 2] = correct;
  ts[t * 4 + 3] = valid;
}

// ---------------- final reduction -> loss, acc ----------------
__global__ void k_finalize(const float* __restrict__ ts, float* __restrict__ out) {
  __shared__ float r0[256], r1[256], r2[256], r3[256];
  int tid = threadIdx.x;
  float s0 = 0, s1 = 0, s2 = 0, s3 = 0;
  for (int t = tid; t < NTOK_; t += 256) {
    s0 += ts[t * 4 + 0]; s1 += ts[t * 4 + 1];
    s2 += ts[t * 4 + 2]; s3 += ts[t * 4 + 3];
  }
  r0[tid] = s0; r1[tid] = s1; r2[tid] = s2; r3[tid] = s3;
  __syncthreads();
  for (int s = 128; s; s >>= 1) {
    if (tid < s) {
      r0[tid] += r0[tid + s]; r1[tid] += r1[tid + s];
      r2[tid] += r2[tid + s]; r3[tid] += r3[tid + s];
    }
    __syncthreads();
  }
  if (tid == 0) {
    out[0] = r0[0] / fmaxf(r1[0], 1e-6f);
    out[1] = r2[0] / fmaxf(r3[0], 1.f);
  }
}

extern "C" void kernel_launch(void* const* d_in, const int* in_sizes, int n_in,
                              void* d_out, int out_size, void* d_ws, size_t ws_size,
                              hipStream_t stream) {
  const int* input_ids = (const int*)d_in[0];
  const float* hs = (const float*)d_in[1];
  const float* lm_head = (const float*)d_in[3];
  const float* norm_w = (const float*)d_in[4];
  const int* anchors = (const int*)d_in[5];
  const float* ctx_w = (const float*)d_in[6];
  const float* embed = (const float*)d_in[7];
  const float* wq = (const float*)d_in[8];
  const float* wk = (const float*)d_in[9];
  const float* wv = (const float*)d_in[10];
  const float* wo = (const float*)d_in[11];
  float* out = (float*)d_out;

  float* ws = (float*)d_ws;
  float* x_kv = ws;      ws += (size_t)B_ * KV_ * D_;    // 12.58M
  float* kbuf = ws;      ws += (size_t)B_ * KV_ * D_;
  float* vbuf = ws;      ws += (size_t)B_ * KV_ * D_;
  float* qbuf = ws;      ws += (size_t)B_ * Q_ * D_;     // 4.19M
  float* attn_out = ws;  ws += (size_t)B_ * Q_ * D_;
  float* proj = ws;      ws += (size_t)B_ * Q_ * D_;
  float* hidden_n = ws;  ws += (size_t)B_ * Q_ * D_;
  float* pm = ws;        ws += (size_t)NTOK_ * VTILES_;
  float* psum = ws;      ws += (size_t)NTOK_ * VTILES_;
  float* plab = ws;      ws += (size_t)NTOK_ * VTILES_;
  int* pbi = (int*)ws;   ws += (size_t)NTOK_ * VTILES_;
  float* tstats = ws;    ws += (size_t)NTOK_ * 4;
  int* dids = (int*)ws;  ws += NTOK_;
  int* dpos = (int*)ws;  ws += NTOK_;
  int* labels = (int*)ws;

  // 1. meta
  k_meta<<<(NTOK_ + 255) / 256, 256, 0, stream>>>(input_ids, anchors, dids, dpos, labels);
  // 2. embedding gather -> x_kv draft rows
  k_gather<<<NTOK_, 256, 0, stream>>>(embed, dids, x_kv);
  // 3. ctx projection -> x_kv ctx rows (M=4096, N=2048, K=6144), ctx-cat A gather
  k_sgemm_nt<1, 0><<<(4096 / 64) * (2048 / 64), 256, 0, stream>>>(
      hs, ctx_w, x_kv, 2048, 6144, 2048, 0, 0LL, 11, (long long)Q_ * D_,
      nullptr, nullptr, nullptr, nullptr, nullptr);
  // 4. K = x_kv @ wk^T (M=6144)
  k_sgemm_nt<0, 0><<<(6144 / 64) * (2048 / 64), 256, 0, stream>>>(
      x_kv, wk, kbuf, 2048, 2048, 2048, 0, 0LL, 0, 0LL,
      nullptr, nullptr, nullptr, nullptr, nullptr);
  // 5. V = x_kv @ wv^T
  k_sgemm_nt<0, 0><<<(6144 / 64) * (2048 / 64), 256, 0, stream>>>(
      x_kv, wv, vbuf, 2048, 2048, 2048, 0, 0LL, 0, 0LL,
      nullptr, nullptr, nullptr, nullptr, nullptr);
  // 6. Q = emb @ wq^T (A = x_kv draft rows with per-batch bump)
  k_sgemm_nt<0, 0><<<(2048 / 64) * (2048 / 64), 256, 0, stream>>>(
      x_kv + (size_t)S_ * D_, wq, qbuf, 2048, 2048, 2048, 10,
      (long long)(KV_ - Q_) * D_, 0, 0LL,
      nullptr, nullptr, nullptr, nullptr, nullptr);
  // 7. RoPE q, RoPE k
  k_rope<<<(NTOK_ * H_ * 64) / 256, 256, 0, stream>>>(qbuf, dpos, 0);
  k_rope<<<(B_ * KV_ * H_ * 64) / 256, 256, 0, stream>>>(kbuf, dpos, 1);
  // 8. attention
  k_attn<<<(B_ * H_ * Q_) / 4, 256, 0, stream>>>(qbuf, kbuf, vbuf, anchors, attn_out);
  // 9. output projection
  k_sgemm_nt<0, 0><<<(2048 / 64) * (2048 / 64), 256, 0, stream>>>(
      attn_out, wo, proj, 2048, 2048, 2048, 0, 0LL, 0, 0LL,
      nullptr, nullptr, nullptr, nullptr, nullptr);
  // 10. residual + RMSNorm
  k_rmsnorm<<<NTOK_, 256, 0, stream>>>(x_kv, proj, norm_w, hidden_n);
  // 11. LM head with fused softmax partials (M=2048, N=32000, K=2048)
  k_sgemm_nt<0, 1><<<(2048 / 64) * (VOCAB_ / 64), 256, 0, stream>>>(
      hidden_n, lm_head, nullptr, VOCAB_, 2048, 2048, 0, 0LL, 0, 0LL,
      labels, pm, psum, pbi, plab);
  // 12. combine partials
  k_combine<<<(NTOK_ + 255) / 256, 256, 0, stream>>>(pm, psum, pbi, plab, labels, tstats);
  // 13. final loss/acc
  k_finalize<<<1, 256, 0, stream>>>(tstats, out);
}

// Round 2
// 3029.604 us; speedup vs baseline: 3.3716x; 3.3716x over previous
//
#include <hip/hip_runtime.h>

#define B_ 2
#define S_ 2048
#define D_ 2048
#define L_ 3
#define H_ 16
#define DH_ 128
#define BLK_ 16
#define NA_ 64
#define Q_ 1024
#define KV_ 3072
#define VOCAB_ 32000
#define MASK_ID_ 31999
#define NTOK_ (B_*Q_)          // 2048
#define VTILES_ (VOCAB_/128)   // 250

typedef __attribute__((ext_vector_type(8))) short bf16x8;
typedef __attribute__((ext_vector_type(4))) float f32x4;
typedef const __attribute__((address_space(1))) void* gptr_t;
typedef __attribute__((address_space(3))) void* lptr_t;

__device__ inline unsigned short f2bf(float x) {
  unsigned int u = __float_as_uint(x);
  unsigned int r = (u + 0x7fff + ((u >> 16) & 1)) >> 16;
  return (unsigned short)r;
}
__device__ inline float bf2f(unsigned short u) {
  return __uint_as_float(((unsigned int)u) << 16);
}

// ---------------- meta ----------------
__global__ void k_meta(const int* __restrict__ ids, const int* __restrict__ anchors,
                       int* __restrict__ dids, int* __restrict__ dpos, int* __restrict__ labels) {
  int t = blockIdx.x * 256 + threadIdx.x;
  if (t >= NTOK_) return;
  int b = t >> 10, qi = t & 1023;
  int a = qi >> 4, off = qi & 15;
  int ap = anchors[b * NA_ + a];
  dpos[t] = ap + off;
  dids[t] = (off == 0) ? ids[b * S_ + ap] : MASK_ID_;
  labels[t] = (off == 0) ? -100 : ids[b * S_ + ap + off];
}

// ---------------- f32 -> bf16 convert (n divisible by 4) ----------------
__global__ void k_cvt(const float* __restrict__ in, unsigned short* __restrict__ out, int n4) {
  int i = blockIdx.x * 256 + threadIdx.x;
  if (i >= n4) return;
  float4 v = ((const float4*)in)[i];
  ushort4 o;
  o.x = f2bf(v.x); o.y = f2bf(v.y); o.z = f2bf(v.z); o.w = f2bf(v.w);
  ((ushort4*)out)[i] = o;
}

// ---------------- ctx_cat gather+convert: out[b*S+s][l*D+d] = hs[l][b][s][d] ----------------
__global__ void k_cvt_ctx(const float* __restrict__ hs, unsigned short* __restrict__ out) {
  int bi = blockIdx.x;          // row*3 + l
  int l = bi % 3, row = bi / 3; // row = b*S+s
  const float4* src = (const float4*)(hs + ((size_t)l * B_ * S_ + row) * (size_t)D_);
  ushort4* dst = (ushort4*)(out + (size_t)row * (3 * D_) + (size_t)l * D_);
  for (int i = threadIdx.x; i < D_ / 4; i += 256) {
    float4 v = src[i];
    ushort4 o;
    o.x = f2bf(v.x); o.y = f2bf(v.y); o.z = f2bf(v.z); o.w = f2bf(v.w);
    dst[i] = o;
  }
}

// ---------------- embedding gather -> bf16 draft rows of x_kv ----------------
__global__ void k_gather(const float* __restrict__ table, const int* __restrict__ dids,
                         unsigned short* __restrict__ x_kv) {
  int row = blockIdx.x;                 // 0..NTOK_
  int b = row >> 10, qi = row & 1023;
  const float4* src = (const float4*)(table + (size_t)dids[row] * D_);
  ushort4* dst = (ushort4*)(x_kv + ((size_t)b * KV_ + S_ + qi) * D_);
  for (int i = threadIdx.x; i < D_ / 4; i += 256) {
    float4 v = src[i];
    ushort4 o;
    o.x = f2bf(v.x); o.y = f2bf(v.y); o.z = f2bf(v.z); o.w = f2bf(v.w);
    dst[i] = o;
  }
}

// ---------------- bf16 MFMA GEMM (m97 structure): C[M,N] = A[M,K] @ Bw[N,K]^T ----------------
// 128x128 tile, BK=32, 4 waves (2x2), each wave 64x64 via 4x4 16x16x32 MFMA frags.
// A source row r -> addr r*K + (r>>adivlog)*abump  (abump=0 for plain)
// CMODE 0: f32 store,  row addr = r*N + (r>>cdivlog)*cbump
// CMODE 1: bf16 store, same addressing
// CMODE 2: LM-head fused softmax partials per 128-col tile
template <int CMODE>
__global__ __launch_bounds__(256) void k_mfma_bt(
    const unsigned short* __restrict__ A, const unsigned short* __restrict__ Bw,
    float* __restrict__ Cf, unsigned short* __restrict__ Cb,
    int M, int N, int K, int adivlog, long long abump, int cdivlog, long long cbump,
    const int* __restrict__ labels, float* __restrict__ pm, float* __restrict__ ps,
    int* __restrict__ pbi, float* __restrict__ plab) {
  __shared__ unsigned short As[128 * 32];
  __shared__ unsigned short Bs[128 * 32];
  int ntn = N >> 7;
  int bx = blockIdx.x % ntn, by = blockIdx.x / ntn;
  int rowbase = by << 7, colbase = bx << 7;
  int tid = threadIdx.x, lane = tid & 63, w = tid >> 6;
  int wr = w >> 1, wc = w & 1;
  int lo = lane & 15, hi = lane >> 4;

  f32x4 acc[4][4];
#pragma unroll
  for (int m = 0; m < 4; ++m)
#pragma unroll
    for (int n = 0; n < 4; ++n) acc[m][n] = (f32x4){0.f, 0.f, 0.f, 0.f};

  for (int kt = 0; kt < K; kt += 32) {
#pragma unroll
    for (int i = 0; i < 2; ++i) {
      int seg = i * 4 + w;                       // 0..7, wave-uniform
      int rloc = seg * 16 + (lane >> 2);         // row within tile
      int kcol = kt + ((lane & 3) << 3);
      int ra = rowbase + rloc;
      long long aoff = (long long)ra * K + (long long)(ra >> adivlog) * abump + kcol;
      __builtin_amdgcn_global_load_lds((gptr_t)(A + aoff), (lptr_t)(As + seg * 512), 16, 0, 0);
      int rb = colbase + rloc;
      long long boff = (long long)rb * K + kcol;
      __builtin_amdgcn_global_load_lds((gptr_t)(Bw + boff), (lptr_t)(Bs + seg * 512), 16, 0, 0);
    }
    __syncthreads();
    bf16x8 af[4], bfv[4];
#pragma unroll
    for (int m = 0; m < 4; ++m) {
      int row = wr * 64 + m * 16 + lo;
      af[m] = *(const bf16x8*)(As + row * 32 + (hi << 3));
    }
#pragma unroll
    for (int n = 0; n < 4; ++n) {
      int row = wc * 64 + n * 16 + lo;
      bfv[n] = *(const bf16x8*)(Bs + row * 32 + (hi << 3));
    }
#pragma unroll
    for (int m = 0; m < 4; ++m)
#pragma unroll
      for (int n = 0; n < 4; ++n)
        acc[m][n] = __builtin_amdgcn_mfma_f32_16x16x32_bf16(af[m], bfv[n], acc[m][n], 0, 0, 0);
    __syncthreads();
  }

  if (CMODE == 0 || CMODE == 1) {
#pragma unroll
    for (int m = 0; m < 4; ++m)
#pragma unroll
      for (int n = 0; n < 4; ++n)
#pragma unroll
        for (int r4 = 0; r4 < 4; ++r4) {
          int row = rowbase + wr * 64 + m * 16 + hi * 4 + r4;
          int col = colbase + wc * 64 + n * 16 + lo;
          size_t addr = (size_t)row * N + (size_t)(row >> cdivlog) * cbump + col;
          if (CMODE == 0) Cf[addr] = acc[m][n][r4];
          else Cb[addr] = f2bf(acc[m][n][r4]);
        }
  } else {
    // LM-head epilogue: per-row (128) max/argmax/sumexp/label-logit over this 128-col tile
    float* f = (float*)As;   // [0:256) rowmax[wc][row], [256:512) rowsum, [512:640) gmax, [640:768) lablogit
    int* ii = (int*)Bs;      // [0:256) rowarg, [256:384) labels, [384:512) garg
    if (tid < 128) { f[640 + tid] = -3.0e38f; ii[256 + tid] = labels[rowbase + tid]; }
    __syncthreads();
    // phase 1: row max/argmax within this wave's 64-col half
#pragma unroll
    for (int m = 0; m < 4; ++m)
#pragma unroll
      for (int r4 = 0; r4 < 4; ++r4) {
        int trow = wr * 64 + m * 16 + hi * 4 + r4;
        float mx = acc[m][0][r4];
        int arg = colbase + wc * 64 + 0 * 16 + lo;
#pragma unroll
        for (int n = 1; n < 4; ++n) {
          float v = acc[m][n][r4];
          int c = colbase + wc * 64 + n * 16 + lo;
          if (v > mx || (v == mx && c < arg)) { mx = v; arg = c; }
        }
#pragma unroll
        for (int d = 1; d < 16; d <<= 1) {
          float om = __shfl_xor(mx, d);
          int oc = __shfl_xor(arg, d);
          if (om > mx || (om == mx && oc < arg)) { mx = om; arg = oc; }
        }
        if (lo == 0) { f[wc * 128 + trow] = mx; ii[wc * 128 + trow] = arg; }
      }
    __syncthreads();
    if (tid < 128) {
      float a = f[tid], b = f[128 + tid];
      int aa = ii[tid], bb = ii[128 + tid];
      float g; int ga;
      if (b > a || (b == a && bb < aa)) { g = b; ga = bb; } else { g = a; ga = aa; }
      f[512 + tid] = g; ii[384 + tid] = ga;
    }
    __syncthreads();
    // phase 2: sumexp with global row max + label-logit capture
#pragma unroll
    for (int m = 0; m < 4; ++m)
#pragma unroll
      for (int r4 = 0; r4 < 4; ++r4) {
        int trow = wr * 64 + m * 16 + hi * 4 + r4;
        float gm = f[512 + trow];
        float s = 0.f;
#pragma unroll
        for (int n = 0; n < 4; ++n) s += __expf(acc[m][n][r4] - gm);
#pragma unroll
        for (int d = 1; d < 16; d <<= 1) s += __shfl_xor(s, d);
        if (lo == 0) f[256 + wc * 128 + trow] = s;
        int lab = ii[256 + trow];
        int rel = lab - colbase - wc * 64;
        if (rel >= 0 && rel < 64 && (rel & 15) == lo) {
#pragma unroll
          for (int n = 0; n < 4; ++n)
            if ((rel >> 4) == n) f[640 + trow] = acc[m][n][r4];
        }
      }
    __syncthreads();
    if (tid < 128) {
      int grow = rowbase + tid;
      size_t p = (size_t)grow * VTILES_ + bx;
      pm[p] = f[512 + tid];
      ps[p] = f[256 + tid] + f[256 + 128 + tid];
      pbi[p] = ii[384 + tid];
      plab[p] = f[640 + tid];
    }
  }
}

// ---------------- RoPE in-place on bf16. mode 0: q rows (B*Q). mode 1: k rows (B*KV) ----------------
__global__ void k_rope(unsigned short* __restrict__ x, const int* __restrict__ dpos, int mode) {
  int idx = blockIdx.x * 256 + threadIdx.x;   // (row, h, j)
  int j = idx & 63;
  int h = (idx >> 6) & 15;
  int row = idx >> 10;
  int pos;
  if (mode == 0) {
    if (row >= NTOK_) return;
    pos = dpos[row];
  } else {
    if (row >= B_ * KV_) return;
    int b = row / KV_, kvi = row % KV_;
    pos = (kvi < S_) ? kvi : dpos[b * Q_ + (kvi - S_)];
  }
  float inv = expf(-(float)j * (9.210340371976184f / 64.f));
  float ang = (float)pos * inv;
  float c = cosf(ang), s = sinf(ang);
  unsigned short* p = x + (size_t)row * D_ + h * DH_ + j;
  float x1 = bf2f(p[0]), x2 = bf2f(p[64]);
  p[0] = f2bf(x1 * c - x2 * s);
  p[64] = f2bf(x2 * c + x1 * s);
}

// ---------------- attention: 2 queries per wave, online softmax, bf16 in/out ----------------
__global__ __launch_bounds__(256) void k_attn(
    const unsigned short* __restrict__ qb, const unsigned short* __restrict__ kb,
    const unsigned short* __restrict__ vb, const int* __restrict__ anchors,
    unsigned short* __restrict__ ob) {
  int wid = (blockIdx.x << 2) + (threadIdx.x >> 6);  // pair id 0..B*H*Q/2-1
  int lane = threadIdx.x & 63;
  int half = lane >> 5, l32 = lane & 31;
  int pi = wid & (Q_ / 2 - 1);
  int qi = pi * 2 + half;
  int h = (wid >> 9) & (H_ - 1);
  int b = wid >> 13;
  int apos = anchors[b * NA_ + (qi >> 4)];
  const float scl = 0.08838834764831845f;  // 1/sqrt(128)
  const unsigned short* qrow = qb + ((size_t)(b * Q_ + qi)) * D_ + h * DH_ + l32 * 4;
  ushort4 qu = *(const ushort4*)qrow;
  float q0 = bf2f(qu.x) * scl, q1 = bf2f(qu.y) * scl, q2 = bf2f(qu.z) * scl, q3 = bf2f(qu.w) * scl;
  const unsigned short* kb0 = kb + ((size_t)b * KV_) * D_ + h * DH_ + l32 * 4;
  const unsigned short* vb0 = vb + ((size_t)b * KV_) * D_ + h * DH_ + l32 * 4;
  float m = -3.0e38f, l = 0.f, a0 = 0.f, a1 = 0.f, a2 = 0.f, a3 = 0.f;
  int dstart = S_ + (qi >> 4) * BLK_;
  int nkeys = apos + BLK_;
  for (int k = 0; k < nkeys; ++k) {
    int kk = (k < apos) ? k : (dstart + (k - apos));
    ushort4 ku = *(const ushort4*)(kb0 + (size_t)kk * D_);
    ushort4 vu = *(const ushort4*)(vb0 + (size_t)kk * D_);
    float part = q0 * bf2f(ku.x) + q1 * bf2f(ku.y) + q2 * bf2f(ku.z) + q3 * bf2f(ku.w);
#pragma unroll
    for (int off = 16; off; off >>= 1) part += __shfl_xor(part, off);
    float mn = fmaxf(m, part);
    float corr = __expf(m - mn);
    float p = __expf(part - mn);
    l = l * corr + p;
    a0 = a0 * corr + p * bf2f(vu.x);
    a1 = a1 * corr + p * bf2f(vu.y);
    a2 = a2 * corr + p * bf2f(vu.z);
    a3 = a3 * corr + p * bf2f(vu.w);
    m = mn;
  }
  float invl = 1.f / l;
  ushort4 o;
  o.x = f2bf(a0 * invl); o.y = f2bf(a1 * invl); o.z = f2bf(a2 * invl); o.w = f2bf(a3 * invl);
  *(ushort4*)(ob + ((size_t)(b * Q_ + qi)) * D_ + h * DH_ + l32 * 4) = o;
}

// ---------------- residual + RMSNorm: hidden = norm(emb_bf + proj_f32) -> bf16 ----------------
__global__ void k_rmsnorm(const unsigned short* __restrict__ x_kv, const float* __restrict__ proj,
                          const float* __restrict__ nw, unsigned short* __restrict__ outp) {
  int row = blockIdx.x;   // 0..NTOK_
  int b = row >> 10, qi = row & 1023;
  const unsigned short* emb = x_kv + ((size_t)b * KV_ + S_ + qi) * D_;
  const float* pr = proj + (size_t)row * D_;
  __shared__ float red[256];
  float h[8];
  float ssum = 0.f;
#pragma unroll
  for (int i = 0; i < 8; ++i) {
    int d = threadIdx.x + i * 256;
    h[i] = bf2f(emb[d]) + pr[d];
    ssum += h[i] * h[i];
  }
  red[threadIdx.x] = ssum;
  __syncthreads();
  for (int s = 128; s; s >>= 1) {
    if (threadIdx.x < s) red[threadIdx.x] += red[threadIdx.x + s];
    __syncthreads();
  }
  float scale = rsqrtf(red[0] / (float)D_ + 1e-6f);
#pragma unroll
  for (int i = 0; i < 8; ++i) {
    int d = threadIdx.x + i * 256;
    outp[(size_t)row * D_ + d] = f2bf(h[i] * scale * nw[d]);
  }
}

// ---------------- combine LM-head partials -> per-token stats ----------------
__global__ void k_combine(const float* __restrict__ pm, const float* __restrict__ ps,
                          const int* __restrict__ pbi, const float* __restrict__ plab,
                          const int* __restrict__ labels, float* __restrict__ ts) {
  int t = blockIdx.x * 256 + threadIdx.x;
  if (t >= NTOK_) return;
  const float* pmr = pm + (size_t)t * VTILES_;
  const float* psr = ps + (size_t)t * VTILES_;
  const int* pbir = pbi + (size_t)t * VTILES_;
  const float* plabr = plab + (size_t)t * VTILES_;
  float M = -3.0e38f; int bi = 0;
  for (int x = 0; x < VTILES_; ++x) {
    float v = pmr[x];
    if (v > M) { M = v; bi = pbir[x]; }
  }
  float ssum = 0.f, labl = -3.0e38f;
  for (int x = 0; x < VTILES_; ++x) {
    ssum += psr[x] * __expf(pmr[x] - M);
    labl = fmaxf(labl, plabr[x]);
  }
  float lse = M + logf(ssum);
  int lab = labels[t];
  int off = t & 15;
  float valid = (lab != -100) ? 1.f : 0.f;
  float w = (off == 0) ? 0.f : __expf(-(float)(off - 1) / 7.0f);
  w *= valid;
  float nll = (lab != -100) ? (lse - labl) : 0.f;
  float correct = (valid > 0.f && bi == lab) ? 1.f : 0.f;
  ts[t * 4 + 0] = nll * w;
  ts[t * 4 + 1] = w;
  ts[t * 4 + 2] = correct;
  ts[t * 4 + 3] = valid;
}

// ---------------- final reduction -> loss, acc ----------------
__global__ void k_finalize(const float* __restrict__ ts, float* __restrict__ out) {
  __shared__ float r0[256], r1[256], r2[256], r3[256];
  int tid = threadIdx.x;
  float s0 = 0, s1 = 0, s2 = 0, s3 = 0;
  for (int t = tid; t < NTOK_; t += 256) {
    s0 += ts[t * 4 + 0]; s1 += ts[t * 4 + 1];
    s2 += ts[t * 4 + 2]; s3 += ts[t * 4 + 3];
  }
  r0[tid] = s0; r1[tid] = s1; r2[tid] = s2; r3[tid] = s3;
  __syncthreads();
  for (int s = 128; s; s >>= 1) {
    if (tid < s) {
      r0[tid] += r0[tid + s]; r1[tid] += r1[tid + s];
      r2[tid] += r2[tid + s]; r3[tid] += r3[tid + s];
    }
    __syncthreads();
  }
  if (tid == 0) {
    out[0] = r0[0] / fmaxf(r1[0], 1e-6f);
    out[1] = r2[0] / fmaxf(r3[0], 1.f);
  }
}

extern "C" void kernel_launch(void* const* d_in, const int* in_sizes, int n_in,
                              void* d_out, int out_size, void* d_ws, size_t ws_size,
                              hipStream_t stream) {
  const int* input_ids = (const int*)d_in[0];
  const float* hs = (const float*)d_in[1];
  const float* lm_head = (const float*)d_in[3];
  const float* norm_w = (const float*)d_in[4];
  const int* anchors = (const int*)d_in[5];
  const float* ctx_w = (const float*)d_in[6];
  const float* embed = (const float*)d_in[7];
  const float* wq = (const float*)d_in[8];
  const float* wk = (const float*)d_in[9];
  const float* wv = (const float*)d_in[10];
  const float* wo = (const float*)d_in[11];
  float* out = (float*)d_out;

  char* base = (char*)d_ws;
  size_t off = 0;
  unsigned short* x_kv_bf = (unsigned short*)(base + off); off += (size_t)B_ * KV_ * D_ * 2;   // 25.2 MB
  unsigned short* wkb = (unsigned short*)(base + off); off += (size_t)D_ * D_ * 2;
  unsigned short* wvb = (unsigned short*)(base + off); off += (size_t)D_ * D_ * 2;
  unsigned short* wqb = (unsigned short*)(base + off); off += (size_t)D_ * D_ * 2;
  unsigned short* wob = (unsigned short*)(base + off); off += (size_t)D_ * D_ * 2;
  unsigned short* hidden_bf = (unsigned short*)(base + off); off += (size_t)NTOK_ * D_ * 2;
  unsigned short* attn_bf = (unsigned short*)(base + off); off += (size_t)NTOK_ * D_ * 2;
  float* proj = (float*)(base + off); off += (size_t)NTOK_ * D_ * 4;
  float* pm = (float*)(base + off); off += (size_t)NTOK_ * VTILES_ * 4;
  float* psum = (float*)(base + off); off += (size_t)NTOK_ * VTILES_ * 4;
  float* plab = (float*)(base + off); off += (size_t)NTOK_ * VTILES_ * 4;
  int* pbi = (int*)(base + off); off += (size_t)NTOK_ * VTILES_ * 4;
  float* tstats = (float*)(base + off); off += (size_t)NTOK_ * 4 * 4;
  int* dids = (int*)(base + off); off += NTOK_ * 4;
  int* dpos = (int*)(base + off); off += NTOK_ * 4;
  int* labels = (int*)(base + off); off += NTOK_ * 4;
  // REGION A (aliased): [ctxA | ctx_wbf | kbuf | vbuf | qbuf] later reused as lm_bf
  char* regA = base + off;
  unsigned short* ctxA = (unsigned short*)(regA);                                   // 50.3 MB
  unsigned short* ctx_wbf = (unsigned short*)(regA + 50331648);                     // 25.2 MB
  unsigned short* kbuf = (unsigned short*)(regA + 50331648 + 25165824);             // 25.2 MB
  unsigned short* vbuf = (unsigned short*)(regA + 50331648 + 2 * 25165824);         // 25.2 MB
  unsigned short* qbuf = (unsigned short*)(regA + 50331648 + 3 * 25165824);         // 8.4 MB
  unsigned short* lm_bf = (unsigned short*)(regA);                                  // 131 MB alias

  // 1. meta + conversions
  k_meta<<<(NTOK_ + 255) / 256, 256, 0, stream>>>(input_ids, anchors, dids, dpos, labels);
  k_cvt<<<((D_ * (L_ * D_) / 4) + 255) / 256, 256, 0, stream>>>(ctx_w, ctx_wbf, D_ * (L_ * D_) / 4);
  k_cvt<<<((D_ * D_ / 4) + 255) / 256, 256, 0, stream>>>(wk, wkb, D_ * D_ / 4);
  k_cvt<<<((D_ * D_ / 4) + 255) / 256, 256, 0, stream>>>(wv, wvb, D_ * D_ / 4);
  k_cvt<<<((D_ * D_ / 4) + 255) / 256, 256, 0, stream>>>(wq, wqb, D_ * D_ / 4);
  k_cvt<<<((D_ * D_ / 4) + 255) / 256, 256, 0, stream>>>(wo, wob, D_ * D_ / 4);
  k_cvt_ctx<<<B_ * S_ * L_, 256, 0, stream>>>(hs, ctxA);
  k_gather<<<NTOK_, 256, 0, stream>>>(embed, dids, x_kv_bf);

  // 2. ctx projection -> x_kv ctx rows (M=4096,N=2048,K=6144), bf16 out with row bump
  k_mfma_bt<1><<<(4096 / 128) * (2048 / 128), 256, 0, stream>>>(
      ctxA, ctx_wbf, nullptr, x_kv_bf, 4096, 2048, 6144, 30, 0LL, 11, (long long)Q_ * D_,
      nullptr, nullptr, nullptr, nullptr, nullptr);
  // 3. K = x_kv @ wk^T (M=6144) bf16
  k_mfma_bt<1><<<(6144 / 128) * (2048 / 128), 256, 0, stream>>>(
      x_kv_bf, wkb, nullptr, kbuf, 6144, 2048, 2048, 30, 0LL, 30, 0LL,
      nullptr, nullptr, nullptr, nullptr, nullptr);
  // 4. V
  k_mfma_bt<1><<<(6144 / 128) * (2048 / 128), 256, 0, stream>>>(
      x_kv_bf, wvb, nullptr, vbuf, 6144, 2048, 2048, 30, 0LL, 30, 0LL,
      nullptr, nullptr, nullptr, nullptr, nullptr);
  // 5. Q = draft rows @ wq^T (A row bump across batches)
  k_mfma_bt<1><<<(2048 / 128) * (2048 / 128), 256, 0, stream>>>(
      x_kv_bf + (size_t)S_ * D_, wqb, nullptr, qbuf, 2048, 2048, 2048, 10,
      (long long)(KV_ - Q_) * D_, 30, 0LL,
      nullptr, nullptr, nullptr, nullptr, nullptr);
  // 6. RoPE
  k_rope<<<(NTOK_ * H_ * 64) / 256, 256, 0, stream>>>(qbuf, dpos, 0);
  k_rope<<<(B_ * KV_ * H_ * 64) / 256, 256, 0, stream>>>(kbuf, dpos, 1);
  // 7. attention
  k_attn<<<(B_ * H_ * Q_ / 2) / 4, 256, 0, stream>>>(qbuf, kbuf, vbuf, anchors, attn_bf);
  // 8. output projection -> f32
  k_mfma_bt<0><<<(2048 / 128) * (2048 / 128), 256, 0, stream>>>(
      attn_bf, wob, proj, nullptr, 2048, 2048, 2048, 30, 0LL, 30, 0LL,
      nullptr, nullptr, nullptr, nullptr, nullptr);
  // 9. residual + RMSNorm -> bf16
  k_rmsnorm<<<NTOK_, 256, 0, stream>>>(x_kv_bf, proj, norm_w, hidden_bf);
  // 10. convert LM head (aliases REGION A — kbuf/vbuf/qbuf/ctxA all dead now)
  k_cvt<<<((VOCAB_ * D_ / 4) + 255) / 256, 256, 0, stream>>>(lm_head, lm_bf, VOCAB_ * D_ / 4);
  // 11. LM head with fused softmax partials (M=2048, N=32000, K=2048)
  k_mfma_bt<2><<<(2048 / 128) * (VOCAB_ / 128), 256, 0, stream>>>(
      hidden_bf, lm_bf, nullptr, nullptr, 2048, VOCAB_, 2048, 30, 0LL, 30, 0LL,
      labels, pm, psum, pbi, plab);
  // 12. combine + finalize
  k_combine<<<(NTOK_ + 255) / 256, 256, 0, stream>>>(pm, psum, pbi, plab, labels, tstats);
  k_finalize<<<1, 256, 0, stream>>>(tstats, out);
}

// Round 3
// 1375.695 us; speedup vs baseline: 7.4252x; 2.2022x over previous
//
#include <hip/hip_runtime.h>

#define B_ 2
#define S_ 2048
#define D_ 2048
#define L_ 3
#define H_ 16
#define DH_ 128
#define BLK_ 16
#define NA_ 64
#define Q_ 1024
#define KV_ 3072
#define VOCAB_ 32000
#define MASK_ID_ 31999
#define NTOK_ (B_*Q_)          // 2048
#define VTILES_ (VOCAB_/128)   // 250

typedef __attribute__((ext_vector_type(8))) short bf16x8;
typedef __attribute__((ext_vector_type(4))) float f32x4;
typedef const __attribute__((address_space(1))) void* gptr_t;
typedef __attribute__((address_space(3))) void* lptr_t;

__device__ inline unsigned short f2bf(float x) {
  unsigned int u = __float_as_uint(x);
  unsigned int r = (u + 0x7fff + ((u >> 16) & 1)) >> 16;
  return (unsigned short)r;
}
__device__ inline float bf2f(unsigned short u) {
  return __uint_as_float(((unsigned int)u) << 16);
}

// ---------------- meta ----------------
__global__ void k_meta(const int* __restrict__ ids, const int* __restrict__ anchors,
                       int* __restrict__ dids, int* __restrict__ dpos, int* __restrict__ labels) {
  int t = blockIdx.x * 256 + threadIdx.x;
  if (t >= NTOK_) return;
  int b = t >> 10, qi = t & 1023;
  int a = qi >> 4, off = qi & 15;
  int ap = anchors[b * NA_ + a];
  dpos[t] = ap + off;
  dids[t] = (off == 0) ? ids[b * S_ + ap] : MASK_ID_;
  labels[t] = (off == 0) ? -100 : ids[b * S_ + ap + off];
}

// ---------------- f32 -> bf16 convert (n divisible by 4) ----------------
__global__ void k_cvt(const float* __restrict__ in, unsigned short* __restrict__ out, int n4) {
  int i = blockIdx.x * 256 + threadIdx.x;
  if (i >= n4) return;
  float4 v = ((const float4*)in)[i];
  ushort4 o;
  o.x = f2bf(v.x); o.y = f2bf(v.y); o.z = f2bf(v.z); o.w = f2bf(v.w);
  ((ushort4*)out)[i] = o;
}

// ---------------- ctx_cat gather+convert ----------------
__global__ void k_cvt_ctx(const float* __restrict__ hs, unsigned short* __restrict__ out) {
  int bi = blockIdx.x;          // row*3 + l
  int l = bi % 3, row = bi / 3; // row = b*S+s
  const float4* src = (const float4*)(hs + ((size_t)l * B_ * S_ + row) * (size_t)D_);
  ushort4* dst = (ushort4*)(out + (size_t)row * (3 * D_) + (size_t)l * D_);
  for (int i = threadIdx.x; i < D_ / 4; i += 256) {
    float4 v = src[i];
    ushort4 o;
    o.x = f2bf(v.x); o.y = f2bf(v.y); o.z = f2bf(v.z); o.w = f2bf(v.w);
    dst[i] = o;
  }
}

// ---------------- embedding gather -> bf16 draft rows of x_kv ----------------
__global__ void k_gather(const float* __restrict__ table, const int* __restrict__ dids,
                         unsigned short* __restrict__ x_kv) {
  int row = blockIdx.x;                 // 0..NTOK_
  int b = row >> 10, qi = row & 1023;
  const float4* src = (const float4*)(table + (size_t)dids[row] * D_);
  ushort4* dst = (ushort4*)(x_kv + ((size_t)b * KV_ + S_ + qi) * D_);
  for (int i = threadIdx.x; i < D_ / 4; i += 256) {
    float4 v = src[i];
    ushort4 o;
    o.x = f2bf(v.x); o.y = f2bf(v.y); o.z = f2bf(v.z); o.w = f2bf(v.w);
    dst[i] = o;
  }
}

// ---------------- bf16 MFMA GEMM (m97 structure): C[M,N] = A[M,K] @ Bw[N,K]^T ----------------
// CMODE 0: f32 store   CMODE 1: bf16 store   CMODE 2: LM-head partials
// CMODE 3: bf16 V^T store (vt[b][h][dim][kv]), hardcoded for M=B*KV, N=D
template <int CMODE>
__global__ __launch_bounds__(256) void k_mfma_bt(
    const unsigned short* __restrict__ A, const unsigned short* __restrict__ Bw,
    float* __restrict__ Cf, unsigned short* __restrict__ Cb,
    int M, int N, int K, int adivlog, long long abump, int cdivlog, long long cbump,
    const int* __restrict__ labels, float* __restrict__ pm, float* __restrict__ ps,
    int* __restrict__ pbi, float* __restrict__ plab) {
  __shared__ unsigned short As[128 * 32];
  __shared__ unsigned short Bs[128 * 32];
  int ntn = N >> 7;
  int bx = blockIdx.x % ntn, by = blockIdx.x / ntn;
  int rowbase = by << 7, colbase = bx << 7;
  int tid = threadIdx.x, lane = tid & 63, w = tid >> 6;
  int wr = w >> 1, wc = w & 1;
  int lo = lane & 15, hi = lane >> 4;

  f32x4 acc[4][4];
#pragma unroll
  for (int m = 0; m < 4; ++m)
#pragma unroll
    for (int n = 0; n < 4; ++n) acc[m][n] = (f32x4){0.f, 0.f, 0.f, 0.f};

  for (int kt = 0; kt < K; kt += 32) {
#pragma unroll
    for (int i = 0; i < 2; ++i) {
      int seg = i * 4 + w;                       // 0..7, wave-uniform
      int rloc = seg * 16 + (lane >> 2);         // row within tile
      int kcol = kt + ((lane & 3) << 3);
      int ra = rowbase + rloc;
      long long aoff = (long long)ra * K + (long long)(ra >> adivlog) * abump + kcol;
      __builtin_amdgcn_global_load_lds((gptr_t)(A + aoff), (lptr_t)(As + seg * 512), 16, 0, 0);
      int rb = colbase + rloc;
      long long boff = (long long)rb * K + kcol;
      __builtin_amdgcn_global_load_lds((gptr_t)(Bw + boff), (lptr_t)(Bs + seg * 512), 16, 0, 0);
    }
    __syncthreads();
    bf16x8 af[4], bfv[4];
#pragma unroll
    for (int m = 0; m < 4; ++m) {
      int row = wr * 64 + m * 16 + lo;
      af[m] = *(const bf16x8*)(As + row * 32 + (hi << 3));
    }
#pragma unroll
    for (int n = 0; n < 4; ++n) {
      int row = wc * 64 + n * 16 + lo;
      bfv[n] = *(const bf16x8*)(Bs + row * 32 + (hi << 3));
    }
#pragma unroll
    for (int m = 0; m < 4; ++m)
#pragma unroll
      for (int n = 0; n < 4; ++n)
        acc[m][n] = __builtin_amdgcn_mfma_f32_16x16x32_bf16(af[m], bfv[n], acc[m][n], 0, 0, 0);
    __syncthreads();
  }

  if (CMODE == 0 || CMODE == 1) {
#pragma unroll
    for (int m = 0; m < 4; ++m)
#pragma unroll
      for (int n = 0; n < 4; ++n)
#pragma unroll
        for (int r4 = 0; r4 < 4; ++r4) {
          int row = rowbase + wr * 64 + m * 16 + hi * 4 + r4;
          int col = colbase + wc * 64 + n * 16 + lo;
          size_t addr = (size_t)row * N + (size_t)(row >> cdivlog) * cbump + col;
          if (CMODE == 0) Cf[addr] = acc[m][n][r4];
          else Cb[addr] = f2bf(acc[m][n][r4]);
        }
  } else if (CMODE == 3) {
    // V^T store: row = b*KV + kv (M=6144), col = h*128 + dim
#pragma unroll
    for (int m = 0; m < 4; ++m)
#pragma unroll
      for (int n = 0; n < 4; ++n)
#pragma unroll
        for (int r4 = 0; r4 < 4; ++r4) {
          int row = rowbase + wr * 64 + m * 16 + hi * 4 + r4;
          int col = colbase + wc * 64 + n * 16 + lo;
          int bb = row >= KV_;
          int kv = row - bb * KV_;
          size_t addr = ((size_t)(bb * H_ + (col >> 7)) * 128 + (col & 127)) * KV_ + kv;
          Cb[addr] = f2bf(acc[m][n][r4]);
        }
  } else {
    // LM-head epilogue
    float* f = (float*)As;
    int* ii = (int*)Bs;
    if (tid < 128) { f[640 + tid] = -3.0e38f; ii[256 + tid] = labels[rowbase + tid]; }
    __syncthreads();
#pragma unroll
    for (int m = 0; m < 4; ++m)
#pragma unroll
      for (int r4 = 0; r4 < 4; ++r4) {
        int trow = wr * 64 + m * 16 + hi * 4 + r4;
        float mx = acc[m][0][r4];
        int arg = colbase + wc * 64 + 0 * 16 + lo;
#pragma unroll
        for (int n = 1; n < 4; ++n) {
          float v = acc[m][n][r4];
          int c = colbase + wc * 64 + n * 16 + lo;
          if (v > mx || (v == mx && c < arg)) { mx = v; arg = c; }
        }
#pragma unroll
        for (int d = 1; d < 16; d <<= 1) {
          float om = __shfl_xor(mx, d);
          int oc = __shfl_xor(arg, d);
          if (om > mx || (om == mx && oc < arg)) { mx = om; arg = oc; }
        }
        if (lo == 0) { f[wc * 128 + trow] = mx; ii[wc * 128 + trow] = arg; }
      }
    __syncthreads();
    if (tid < 128) {
      float a = f[tid], b = f[128 + tid];
      int aa = ii[tid], bb = ii[128 + tid];
      float g; int ga;
      if (b > a || (b == a && bb < aa)) { g = b; ga = bb; } else { g = a; ga = aa; }
      f[512 + tid] = g; ii[384 + tid] = ga;
    }
    __syncthreads();
#pragma unroll
    for (int m = 0; m < 4; ++m)
#pragma unroll
      for (int r4 = 0; r4 < 4; ++r4) {
        int trow = wr * 64 + m * 16 + hi * 4 + r4;
        float gm = f[512 + trow];
        float s = 0.f;
#pragma unroll
        for (int n = 0; n < 4; ++n) s += __expf(acc[m][n][r4] - gm);
#pragma unroll
        for (int d = 1; d < 16; d <<= 1) s += __shfl_xor(s, d);
        if (lo == 0) f[256 + wc * 128 + trow] = s;
        int lab = ii[256 + trow];
        int rel = lab - colbase - wc * 64;
        if (rel >= 0 && rel < 64 && (rel & 15) == lo) {
#pragma unroll
          for (int n = 0; n < 4; ++n)
            if ((rel >> 4) == n) f[640 + trow] = acc[m][n][r4];
        }
      }
    __syncthreads();
    if (tid < 128) {
      int grow = rowbase + tid;
      size_t p = (size_t)grow * VTILES_ + bx;
      pm[p] = f[512 + tid];
      ps[p] = f[256 + tid] + f[256 + 128 + tid];
      pbi[p] = ii[384 + tid];
      plab[p] = f[640 + tid];
    }
  }
}

// ---------------- RoPE in-place on bf16 ----------------
__global__ void k_rope(unsigned short* __restrict__ x, const int* __restrict__ dpos, int mode) {
  int idx = blockIdx.x * 256 + threadIdx.x;
  int j = idx & 63;
  int h = (idx >> 6) & 15;
  int row = idx >> 10;
  int pos;
  if (mode == 0) {
    if (row >= NTOK_) return;
    pos = dpos[row];
  } else {
    if (row >= B_ * KV_) return;
    int b = row / KV_, kvi = row % KV_;
    pos = (kvi < S_) ? kvi : dpos[b * Q_ + (kvi - S_)];
  }
  float inv = expf(-(float)j * (9.210340371976184f / 64.f));
  float ang = (float)pos * inv;
  float c = cosf(ang), s = sinf(ang);
  unsigned short* p = x + (size_t)row * D_ + h * DH_ + j;
  float x1 = bf2f(p[0]), x2 = bf2f(p[64]);
  p[0] = f2bf(x1 * c - x2 * s);
  p[64] = f2bf(x2 * c + x1 * s);
}

// ---------------- MFMA flash attention: one wave per (b, anchor-block, h) ----------------
// Swapped QK^T (S^T = K·Q^T) so softmax is lane-local + 2 shfl.
// PV uses pre-transposed V (vt[b][h][dim][kv]) -> contiguous B-frag loads.
__global__ __launch_bounds__(256) void k_attn_mfma(
    const unsigned short* __restrict__ qb, const unsigned short* __restrict__ kb,
    const unsigned short* __restrict__ vt, const int* __restrict__ anchors,
    unsigned short* __restrict__ ob) {
  __shared__ __align__(16) unsigned short P_all[4][16 * 40];
  int w = threadIdx.x >> 6, lane = threadIdx.x & 63;
  int blk = blockIdx.x * 4 + w;            // ((b*NA + a)*H + h)
  int h = blk & 15, a = (blk >> 4) & 63, b = blk >> 10;
  int ql = lane & 15, p = lane >> 4;
  int apos = anchors[b * NA_ + a];
  unsigned short* P = P_all[w];

  // Q B-frags (row slices of Q): 4 k-steps of 32 dims
  const unsigned short* qbase = qb + ((size_t)(b * Q_ + a * 16 + ql)) * D_ + h * DH_;
  bf16x8 qf[4];
#pragma unroll
  for (int ks = 0; ks < 4; ++ks)
    qf[ks] = *(const bf16x8*)(qbase + ks * 32 + p * 8);

  const unsigned short* kbb = kb + (size_t)b * KV_ * D_ + h * DH_;
  const unsigned short* vtb = vt + ((size_t)(b * H_ + h)) * 128 * KV_;

  f32x4 o[8];
#pragma unroll
  for (int nt = 0; nt < 8; ++nt) o[nt] = (f32x4){0.f, 0.f, 0.f, 0.f};
  float mrun = -3.0e38f, lrun = 0.f;

  int ncx = (apos + 31) >> 5;
  const float scl = 0.08838834764831845f;

  for (int t = 0; t <= ncx; ++t) {
    int ktb = (t < ncx) ? (t << 5) : (S_ + a * 16);
    int rem = apos - (t << 5);
    int vc = (t < ncx) ? (rem < 32 ? rem : 32) : 16;
    float s[2][4];
#pragma unroll
    for (int g = 0; g < 2; ++g) {
      if (g * 16 < vc) {
        f32x4 accs = (f32x4){0.f, 0.f, 0.f, 0.f};
        const unsigned short* krow = kbb + (size_t)(ktb + g * 16 + ql) * D_;
#pragma unroll
        for (int ks = 0; ks < 4; ++ks) {
          bf16x8 kf = *(const bf16x8*)(krow + ks * 32 + p * 8);
          accs = __builtin_amdgcn_mfma_f32_16x16x32_bf16(kf, qf[ks], accs, 0, 0, 0);
        }
#pragma unroll
        for (int r = 0; r < 4; ++r) {
          int kl = g * 16 + p * 4 + r;
          s[g][r] = (kl < vc) ? accs[r] * scl : -3.0e38f;
        }
      } else {
#pragma unroll
        for (int r = 0; r < 4; ++r) s[g][r] = -3.0e38f;
      }
    }
    // tile max per query (in-lane 8 + xor16 + xor32)
    float mt = s[0][0];
#pragma unroll
    for (int g = 0; g < 2; ++g)
#pragma unroll
      for (int r = 0; r < 4; ++r) mt = fmaxf(mt, s[g][r]);
    mt = fmaxf(mt, __shfl_xor(mt, 16));
    mt = fmaxf(mt, __shfl_xor(mt, 32));
    float mnew = fmaxf(mrun, mt);
    float corr = __expf(mrun - mnew);
    float psum = 0.f;
#pragma unroll
    for (int g = 0; g < 2; ++g) {
      float p0 = __expf(s[g][0] - mnew), p1 = __expf(s[g][1] - mnew);
      float p2 = __expf(s[g][2] - mnew), p3 = __expf(s[g][3] - mnew);
      psum += p0 + p1 + p2 + p3;
      ushort2 w0, w1;
      w0.x = f2bf(p0); w0.y = f2bf(p1); w1.x = f2bf(p2); w1.y = f2bf(p3);
      int eo = ql * 40 + g * 16 + p * 4;
      *(ushort2*)(P + eo) = w0;
      *(ushort2*)(P + eo + 2) = w1;
    }
    psum += __shfl_xor(psum, 16);
    psum += __shfl_xor(psum, 32);
    lrun = lrun * corr + psum;
    mrun = mnew;
    // rescale O by corr of this lane's C rows (queries p*4+r)
    float cr[4];
#pragma unroll
    for (int r = 0; r < 4; ++r) cr[r] = __shfl(corr, p * 4 + r);
#pragma unroll
    for (int nt = 0; nt < 8; ++nt)
#pragma unroll
      for (int r = 0; r < 4; ++r) o[nt][r] *= cr[r];
    // PV
    bf16x8 pf = *(const bf16x8*)(P + ql * 40 + p * 8);
#pragma unroll
    for (int nt = 0; nt < 8; ++nt) {
      bf16x8 vf = *(const bf16x8*)(vtb + (size_t)(nt * 16 + ql) * KV_ + ktb + p * 8);
      o[nt] = __builtin_amdgcn_mfma_f32_16x16x32_bf16(pf, vf, o[nt], 0, 0, 0);
    }
  }
  float lq[4];
#pragma unroll
  for (int r = 0; r < 4; ++r) lq[r] = 1.f / __shfl(lrun, p * 4 + r);
  unsigned short* obase = ob + ((size_t)(b * Q_ + a * 16)) * D_ + h * DH_;
#pragma unroll
  for (int nt = 0; nt < 8; ++nt)
#pragma unroll
    for (int r = 0; r < 4; ++r)
      obase[(size_t)(p * 4 + r) * D_ + nt * 16 + ql] = f2bf(o[nt][r] * lq[r]);
}

// ---------------- residual + RMSNorm ----------------
__global__ void k_rmsnorm(const unsigned short* __restrict__ x_kv, const float* __restrict__ proj,
                          const float* __restrict__ nw, unsigned short* __restrict__ outp) {
  int row = blockIdx.x;
  int b = row >> 10, qi = row & 1023;
  const unsigned short* emb = x_kv + ((size_t)b * KV_ + S_ + qi) * D_;
  const float* pr = proj + (size_t)row * D_;
  __shared__ float red[256];
  float h[8];
  float ssum = 0.f;
#pragma unroll
  for (int i = 0; i < 8; ++i) {
    int d = threadIdx.x + i * 256;
    h[i] = bf2f(emb[d]) + pr[d];
    ssum += h[i] * h[i];
  }
  red[threadIdx.x] = ssum;
  __syncthreads();
  for (int s = 128; s; s >>= 1) {
    if (threadIdx.x < s) red[threadIdx.x] += red[threadIdx.x + s];
    __syncthreads();
  }
  float scale = rsqrtf(red[0] / (float)D_ + 1e-6f);
#pragma unroll
  for (int i = 0; i < 8; ++i) {
    int d = threadIdx.x + i * 256;
    outp[(size_t)row * D_ + d] = f2bf(h[i] * scale * nw[d]);
  }
}

// ---------------- combine LM-head partials ----------------
__global__ void k_combine(const float* __restrict__ pm, const float* __restrict__ ps,
                          const int* __restrict__ pbi, const float* __restrict__ plab,
                          const int* __restrict__ labels, float* __restrict__ ts) {
  int t = blockIdx.x * 256 + threadIdx.x;
  if (t >= NTOK_) return;
  const float* pmr = pm + (size_t)t * VTILES_;
  const float* psr = ps + (size_t)t * VTILES_;
  const int* pbir = pbi + (size_t)t * VTILES_;
  const float* plabr = plab + (size_t)t * VTILES_;
  float M = -3.0e38f; int bi = 0;
  for (int x = 0; x < VTILES_; ++x) {
    float v = pmr[x];
    if (v > M) { M = v; bi = pbir[x]; }
  }
  float ssum = 0.f, labl = -3.0e38f;
  for (int x = 0; x < VTILES_; ++x) {
    ssum += psr[x] * __expf(pmr[x] - M);
    labl = fmaxf(labl, plabr[x]);
  }
  float lse = M + logf(ssum);
  int lab = labels[t];
  int off = t & 15;
  float valid = (lab != -100) ? 1.f : 0.f;
  float w = (off == 0) ? 0.f : __expf(-(float)(off - 1) / 7.0f);
  w *= valid;
  float nll = (lab != -100) ? (lse - labl) : 0.f;
  float correct = (valid > 0.f && bi == lab) ? 1.f : 0.f;
  ts[t * 4 + 0] = nll * w;
  ts[t * 4 + 1] = w;
  ts[t * 4 + 2] = correct;
  ts[t * 4 + 3] = valid;
}

// ---------------- final reduction ----------------
__global__ void k_finalize(const float* __restrict__ ts, float* __restrict__ out) {
  __shared__ float r0[256], r1[256], r2[256], r3[256];
  int tid = threadIdx.x;
  float s0 = 0, s1 = 0, s2 = 0, s3 = 0;
  for (int t = tid; t < NTOK_; t += 256) {
    s0 += ts[t * 4 + 0]; s1 += ts[t * 4 + 1];
    s2 += ts[t * 4 + 2]; s3 += ts[t * 4 + 3];
  }
  r0[tid] = s0; r1[tid] = s1; r2[tid] = s2; r3[tid] = s3;
  __syncthreads();
  for (int s = 128; s; s >>= 1) {
    if (tid < s) {
      r0[tid] += r0[tid + s]; r1[tid] += r1[tid + s];
      r2[tid] += r2[tid + s]; r3[tid] += r3[tid + s];
    }
    __syncthreads();
  }
  if (tid == 0) {
    out[0] = r0[0] / fmaxf(r1[0], 1e-6f);
    out[1] = r2[0] / fmaxf(r3[0], 1.f);
  }
}

extern "C" void kernel_launch(void* const* d_in, const int* in_sizes, int n_in,
                              void* d_out, int out_size, void* d_ws, size_t ws_size,
                              hipStream_t stream) {
  const int* input_ids = (const int*)d_in[0];
  const float* hs = (const float*)d_in[1];
  const float* lm_head = (const float*)d_in[3];
  const float* norm_w = (const float*)d_in[4];
  const int* anchors = (const int*)d_in[5];
  const float* ctx_w = (const float*)d_in[6];
  const float* embed = (const float*)d_in[7];
  const float* wq = (const float*)d_in[8];
  const float* wk = (const float*)d_in[9];
  const float* wv = (const float*)d_in[10];
  const float* wo = (const float*)d_in[11];
  float* out = (float*)d_out;

  char* base = (char*)d_ws;
  size_t off = 0;
  unsigned short* x_kv_bf = (unsigned short*)(base + off); off += (size_t)B_ * KV_ * D_ * 2;
  unsigned short* wkb = (unsigned short*)(base + off); off += (size_t)D_ * D_ * 2;
  unsigned short* wvb = (unsigned short*)(base + off); off += (size_t)D_ * D_ * 2;
  unsigned short* wqb = (unsigned short*)(base + off); off += (size_t)D_ * D_ * 2;
  unsigned short* wob = (unsigned short*)(base + off); off += (size_t)D_ * D_ * 2;
  unsigned short* hidden_bf = (unsigned short*)(base + off); off += (size_t)NTOK_ * D_ * 2;
  unsigned short* attn_bf = (unsigned short*)(base + off); off += (size_t)NTOK_ * D_ * 2;
  float* proj = (float*)(base + off); off += (size_t)NTOK_ * D_ * 4;
  float* pm = (float*)(base + off); off += (size_t)NTOK_ * VTILES_ * 4;
  float* psum = (float*)(base + off); off += (size_t)NTOK_ * VTILES_ * 4;
  float* plab = (float*)(base + off); off += (size_t)NTOK_ * VTILES_ * 4;
  int* pbi = (int*)(base + off); off += (size_t)NTOK_ * VTILES_ * 4;
  float* tstats = (float*)(base + off); off += (size_t)NTOK_ * 4 * 4;
  int* dids = (int*)(base + off); off += NTOK_ * 4;
  int* dpos = (int*)(base + off); off += NTOK_ * 4;
  int* labels = (int*)(base + off); off += NTOK_ * 4;
  // REGION A (aliased): [ctxA | ctx_wbf | kbuf | vtbuf | qbuf] later reused as lm_bf
  char* regA = base + off;
  const size_t SLACK = 65536;
  unsigned short* ctxA = (unsigned short*)(regA);                                   // 50.3 MB
  unsigned short* ctx_wbf = (unsigned short*)(regA + 50331648);                     // 25.2 MB
  unsigned short* kbuf = (unsigned short*)(regA + 50331648 + 25165824);             // 25.2 MB + slack
  unsigned short* vtbuf = (unsigned short*)(regA + 50331648 + 2 * 25165824 + SLACK);// 25.2 MB + slack
  unsigned short* qbuf = (unsigned short*)(regA + 50331648 + 3 * 25165824 + 2 * SLACK);
  unsigned short* lm_bf = (unsigned short*)(regA);                                  // 131 MB alias

  k_meta<<<(NTOK_ + 255) / 256, 256, 0, stream>>>(input_ids, anchors, dids, dpos, labels);
  k_cvt<<<((D_ * (L_ * D_) / 4) + 255) / 256, 256, 0, stream>>>(ctx_w, ctx_wbf, D_ * (L_ * D_) / 4);
  k_cvt<<<((D_ * D_ / 4) + 255) / 256, 256, 0, stream>>>(wk, wkb, D_ * D_ / 4);
  k_cvt<<<((D_ * D_ / 4) + 255) / 256, 256, 0, stream>>>(wv, wvb, D_ * D_ / 4);
  k_cvt<<<((D_ * D_ / 4) + 255) / 256, 256, 0, stream>>>(wq, wqb, D_ * D_ / 4);
  k_cvt<<<((D_ * D_ / 4) + 255) / 256, 256, 0, stream>>>(wo, wob, D_ * D_ / 4);
  k_cvt_ctx<<<B_ * S_ * L_, 256, 0, stream>>>(hs, ctxA);
  k_gather<<<NTOK_, 256, 0, stream>>>(embed, dids, x_kv_bf);

  // ctx projection -> x_kv ctx rows
  k_mfma_bt<1><<<(4096 / 128) * (2048 / 128), 256, 0, stream>>>(
      ctxA, ctx_wbf, nullptr, x_kv_bf, 4096, 2048, 6144, 30, 0LL, 11, (long long)Q_ * D_,
      nullptr, nullptr, nullptr, nullptr, nullptr);
  // K
  k_mfma_bt<1><<<(6144 / 128) * (2048 / 128), 256, 0, stream>>>(
      x_kv_bf, wkb, nullptr, kbuf, 6144, 2048, 2048, 30, 0LL, 30, 0LL,
      nullptr, nullptr, nullptr, nullptr, nullptr);
  // V -> transposed store vt[b][h][dim][kv]
  k_mfma_bt<3><<<(6144 / 128) * (2048 / 128), 256, 0, stream>>>(
      x_kv_bf, wvb, nullptr, vtbuf, 6144, 2048, 2048, 30, 0LL, 30, 0LL,
      nullptr, nullptr, nullptr, nullptr, nullptr);
  // Q
  k_mfma_bt<1><<<(2048 / 128) * (2048 / 128), 256, 0, stream>>>(
      x_kv_bf + (size_t)S_ * D_, wqb, nullptr, qbuf, 2048, 2048, 2048, 10,
      (long long)(KV_ - Q_) * D_, 30, 0LL,
      nullptr, nullptr, nullptr, nullptr, nullptr);
  // RoPE
  k_rope<<<(NTOK_ * H_ * 64) / 256, 256, 0, stream>>>(qbuf, dpos, 0);
  k_rope<<<(B_ * KV_ * H_ * 64) / 256, 256, 0, stream>>>(kbuf, dpos, 1);
  // attention (MFMA flash)
  k_attn_mfma<<<(B_ * NA_ * H_) / 4, 256, 0, stream>>>(qbuf, kbuf, vtbuf, anchors, attn_bf);
  // output projection -> f32
  k_mfma_bt<0><<<(2048 / 128) * (2048 / 128), 256, 0, stream>>>(
      attn_bf, wob, proj, nullptr, 2048, 2048, 2048, 30, 0LL, 30, 0LL,
      nullptr, nullptr, nullptr, nullptr, nullptr);
  // residual + RMSNorm
  k_rmsnorm<<<NTOK_, 256, 0, stream>>>(x_kv_bf, proj, norm_w, hidden_bf);
  // LM head convert (aliases REGION A — all dead now)
  k_cvt<<<((VOCAB_ * D_ / 4) + 255) / 256, 256, 0, stream>>>(lm_head, lm_bf, VOCAB_ * D_ / 4);
  // LM head GEMM + fused softmax partials
  k_mfma_bt<2><<<(2048 / 128) * (VOCAB_ / 128), 256, 0, stream>>>(
      hidden_bf, lm_bf, nullptr, nullptr, 2048, VOCAB_, 2048, 30, 0LL, 30, 0LL,
      labels, pm, psum, pbi, plab);
  k_combine<<<(NTOK_ + 255) / 256, 256, 0, stream>>>(pm, psum, pbi, plab, labels, tstats);
  k_finalize<<<1, 256, 0, stream>>>(tstats, out);
}

// Round 4
// 1374.455 us; speedup vs baseline: 7.4319x; 1.0009x over previous
//
#include <hip/hip_runtime.h>

#define B_ 2
#define S_ 2048
#define D_ 2048
#define L_ 3
#define H_ 16
#define DH_ 128
#define BLK_ 16
#define NA_ 64
#define Q_ 1024
#define KV_ 3072
#define VOCAB_ 32000
#define MASK_ID_ 31999
#define NTOK_ (B_*Q_)          // 2048
#define VTILES_ (VOCAB_/128)   // 250

typedef __attribute__((ext_vector_type(8))) short bf16x8;
typedef __attribute__((ext_vector_type(4))) float f32x4;
typedef const __attribute__((address_space(1))) void* gptr_t;
typedef __attribute__((address_space(3))) void* lptr_t;

__device__ inline unsigned short f2bf(float x) {
  unsigned int u = __float_as_uint(x);
  unsigned int r = (u + 0x7fff + ((u >> 16) & 1)) >> 16;
  return (unsigned short)r;
}
__device__ inline float bf2f(unsigned short u) {
  return __uint_as_float(((unsigned int)u) << 16);
}

// ---------------- meta ----------------
__global__ void k_meta(const int* __restrict__ ids, const int* __restrict__ anchors,
                       int* __restrict__ dids, int* __restrict__ dpos, int* __restrict__ labels) {
  int t = blockIdx.x * 256 + threadIdx.x;
  if (t >= NTOK_) return;
  int b = t >> 10, qi = t & 1023;
  int a = qi >> 4, off = qi & 15;
  int ap = anchors[b * NA_ + a];
  dpos[t] = ap + off;
  dids[t] = (off == 0) ? ids[b * S_ + ap] : MASK_ID_;
  labels[t] = (off == 0) ? -100 : ids[b * S_ + ap + off];
}

// ---------------- f32 -> bf16 convert (n divisible by 4) ----------------
__global__ void k_cvt(const float* __restrict__ in, unsigned short* __restrict__ out, int n4) {
  int i = blockIdx.x * 256 + threadIdx.x;
  if (i >= n4) return;
  float4 v = ((const float4*)in)[i];
  ushort4 o;
  o.x = f2bf(v.x); o.y = f2bf(v.y); o.z = f2bf(v.z); o.w = f2bf(v.w);
  ((ushort4*)out)[i] = o;
}

// ---------------- ctx_cat gather+convert ----------------
__global__ void k_cvt_ctx(const float* __restrict__ hs, unsigned short* __restrict__ out) {
  int bi = blockIdx.x;          // row*3 + l
  int l = bi % 3, row = bi / 3; // row = b*S+s
  const float4* src = (const float4*)(hs + ((size_t)l * B_ * S_ + row) * (size_t)D_);
  ushort4* dst = (ushort4*)(out + (size_t)row * (3 * D_) + (size_t)l * D_);
  for (int i = threadIdx.x; i < D_ / 4; i += 256) {
    float4 v = src[i];
    ushort4 o;
    o.x = f2bf(v.x); o.y = f2bf(v.y); o.z = f2bf(v.z); o.w = f2bf(v.w);
    dst[i] = o;
  }
}

// ---------------- embedding gather -> bf16 draft rows of x_kv ----------------
__global__ void k_gather(const float* __restrict__ table, const int* __restrict__ dids,
                         unsigned short* __restrict__ x_kv) {
  int row = blockIdx.x;                 // 0..NTOK_
  int b = row >> 10, qi = row & 1023;
  const float4* src = (const float4*)(table + (size_t)dids[row] * D_);
  ushort4* dst = (ushort4*)(x_kv + ((size_t)b * KV_ + S_ + qi) * D_);
  for (int i = threadIdx.x; i < D_ / 4; i += 256) {
    float4 v = src[i];
    ushort4 o;
    o.x = f2bf(v.x); o.y = f2bf(v.y); o.z = f2bf(v.z); o.w = f2bf(v.w);
    dst[i] = o;
  }
}

// ---------------- bf16 MFMA GEMM (m97 structure): C[M,N] = A[M,K] @ Bw[N,K]^T ----------------
// CMODE 0: f32 store   CMODE 1: bf16 store   CMODE 2: LM-head partials
// CMODE 3: bf16 V^T store (vt[b][h][dim][kv]), hardcoded for M=B*KV, N=D
// MAP 0: col-tile fastest (A-panel reuse in L2)
// MAP 1: row-tile fastest + XCD-chunked swizzle (B-panel reuse in one XCD's L2;
//        requires gridDim.x % 8 == 0)
template <int CMODE, int MAP>
__global__ __launch_bounds__(256) void k_mfma_bt(
    const unsigned short* __restrict__ A, const unsigned short* __restrict__ Bw,
    float* __restrict__ Cf, unsigned short* __restrict__ Cb,
    int M, int N, int K, int adivlog, long long abump, int cdivlog, long long cbump,
    const int* __restrict__ labels, float* __restrict__ pm, float* __restrict__ ps,
    int* __restrict__ pbi, float* __restrict__ plab) {
  __shared__ unsigned short As[128 * 32];
  __shared__ unsigned short Bs[128 * 32];
  int bx, by;
  if (MAP == 0) {
    int ntn = N >> 7;
    bx = blockIdx.x % ntn, by = blockIdx.x / ntn;
  } else {
    int per = gridDim.x >> 3;
    int wgid = (blockIdx.x & 7) * per + (blockIdx.x >> 3);  // bijective: nwg%8==0
    int ntm = M >> 7;
    by = wgid % ntm, bx = wgid / ntm;
  }
  int rowbase = by << 7, colbase = bx << 7;
  int tid = threadIdx.x, lane = tid & 63, w = tid >> 6;
  int wr = w >> 1, wc = w & 1;
  int lo = lane & 15, hi = lane >> 4;

  f32x4 acc[4][4];
#pragma unroll
  for (int m = 0; m < 4; ++m)
#pragma unroll
    for (int n = 0; n < 4; ++n) acc[m][n] = (f32x4){0.f, 0.f, 0.f, 0.f};

  for (int kt = 0; kt < K; kt += 32) {
#pragma unroll
    for (int i = 0; i < 2; ++i) {
      int seg = i * 4 + w;                       // 0..7, wave-uniform
      int rloc = seg * 16 + (lane >> 2);         // row within tile
      int kcol = kt + ((lane & 3) << 3);
      int ra = rowbase + rloc;
      long long aoff = (long long)ra * K + (long long)(ra >> adivlog) * abump + kcol;
      __builtin_amdgcn_global_load_lds((gptr_t)(A + aoff), (lptr_t)(As + seg * 512), 16, 0, 0);
      int rb = colbase + rloc;
      long long boff = (long long)rb * K + kcol;
      __builtin_amdgcn_global_load_lds((gptr_t)(Bw + boff), (lptr_t)(Bs + seg * 512), 16, 0, 0);
    }
    __syncthreads();
    bf16x8 af[4], bfv[4];
#pragma unroll
    for (int m = 0; m < 4; ++m) {
      int row = wr * 64 + m * 16 + lo;
      af[m] = *(const bf16x8*)(As + row * 32 + (hi << 3));
    }
#pragma unroll
    for (int n = 0; n < 4; ++n) {
      int row = wc * 64 + n * 16 + lo;
      bfv[n] = *(const bf16x8*)(Bs + row * 32 + (hi << 3));
    }
#pragma unroll
    for (int m = 0; m < 4; ++m)
#pragma unroll
      for (int n = 0; n < 4; ++n)
        acc[m][n] = __builtin_amdgcn_mfma_f32_16x16x32_bf16(af[m], bfv[n], acc[m][n], 0, 0, 0);
    __syncthreads();
  }

  if (CMODE == 0 || CMODE == 1) {
#pragma unroll
    for (int m = 0; m < 4; ++m)
#pragma unroll
      for (int n = 0; n < 4; ++n)
#pragma unroll
        for (int r4 = 0; r4 < 4; ++r4) {
          int row = rowbase + wr * 64 + m * 16 + hi * 4 + r4;
          int col = colbase + wc * 64 + n * 16 + lo;
          size_t addr = (size_t)row * N + (size_t)(row >> cdivlog) * cbump + col;
          if (CMODE == 0) Cf[addr] = acc[m][n][r4];
          else Cb[addr] = f2bf(acc[m][n][r4]);
        }
  } else if (CMODE == 3) {
    // V^T store: row = b*KV + kv (M=6144), col = h*128 + dim
#pragma unroll
    for (int m = 0; m < 4; ++m)
#pragma unroll
      for (int n = 0; n < 4; ++n)
#pragma unroll
        for (int r4 = 0; r4 < 4; ++r4) {
          int row = rowbase + wr * 64 + m * 16 + hi * 4 + r4;
          int col = colbase + wc * 64 + n * 16 + lo;
          int bb = row >= KV_;
          int kv = row - bb * KV_;
          size_t addr = ((size_t)(bb * H_ + (col >> 7)) * 128 + (col & 127)) * KV_ + kv;
          Cb[addr] = f2bf(acc[m][n][r4]);
        }
  } else {
    // LM-head epilogue
    float* f = (float*)As;
    int* ii = (int*)Bs;
    if (tid < 128) { f[640 + tid] = -3.0e38f; ii[256 + tid] = labels[rowbase + tid]; }
    __syncthreads();
#pragma unroll
    for (int m = 0; m < 4; ++m)
#pragma unroll
      for (int r4 = 0; r4 < 4; ++r4) {
        int trow = wr * 64 + m * 16 + hi * 4 + r4;
        float mx = acc[m][0][r4];
        int arg = colbase + wc * 64 + 0 * 16 + lo;
#pragma unroll
        for (int n = 1; n < 4; ++n) {
          float v = acc[m][n][r4];
          int c = colbase + wc * 64 + n * 16 + lo;
          if (v > mx || (v == mx && c < arg)) { mx = v; arg = c; }
        }
#pragma unroll
        for (int d = 1; d < 16; d <<= 1) {
          float om = __shfl_xor(mx, d);
          int oc = __shfl_xor(arg, d);
          if (om > mx || (om == mx && oc < arg)) { mx = om; arg = oc; }
        }
        if (lo == 0) { f[wc * 128 + trow] = mx; ii[wc * 128 + trow] = arg; }
      }
    __syncthreads();
    if (tid < 128) {
      float a = f[tid], b = f[128 + tid];
      int aa = ii[tid], bb = ii[128 + tid];
      float g; int ga;
      if (b > a || (b == a && bb < aa)) { g = b; ga = bb; } else { g = a; ga = aa; }
      f[512 + tid] = g; ii[384 + tid] = ga;
    }
    __syncthreads();
#pragma unroll
    for (int m = 0; m < 4; ++m)
#pragma unroll
      for (int r4 = 0; r4 < 4; ++r4) {
        int trow = wr * 64 + m * 16 + hi * 4 + r4;
        float gm = f[512 + trow];
        float s = 0.f;
#pragma unroll
        for (int n = 0; n < 4; ++n) s += __expf(acc[m][n][r4] - gm);
#pragma unroll
        for (int d = 1; d < 16; d <<= 1) s += __shfl_xor(s, d);
        if (lo == 0) f[256 + wc * 128 + trow] = s;
        int lab = ii[256 + trow];
        int rel = lab - colbase - wc * 64;
        if (rel >= 0 && rel < 64 && (rel & 15) == lo) {
#pragma unroll
          for (int n = 0; n < 4; ++n)
            if ((rel >> 4) == n) f[640 + trow] = acc[m][n][r4];
        }
      }
    __syncthreads();
    if (tid < 128) {
      int grow = rowbase + tid;
      size_t p = (size_t)grow * VTILES_ + bx;
      pm[p] = f[512 + tid];
      ps[p] = f[256 + tid] + f[256 + 128 + tid];
      pbi[p] = ii[384 + tid];
      plab[p] = f[640 + tid];
    }
  }
}

// ---------------- RoPE in-place on bf16 ----------------
__global__ void k_rope(unsigned short* __restrict__ x, const int* __restrict__ dpos, int mode) {
  int idx = blockIdx.x * 256 + threadIdx.x;
  int j = idx & 63;
  int h = (idx >> 6) & 15;
  int row = idx >> 10;
  int pos;
  if (mode == 0) {
    if (row >= NTOK_) return;
    pos = dpos[row];
  } else {
    if (row >= B_ * KV_) return;
    int b = row / KV_, kvi = row % KV_;
    pos = (kvi < S_) ? kvi : dpos[b * Q_ + (kvi - S_)];
  }
  float inv = expf(-(float)j * (9.210340371976184f / 64.f));
  float ang = (float)pos * inv;
  float c = cosf(ang), s = sinf(ang);
  unsigned short* p = x + (size_t)row * D_ + h * DH_ + j;
  float x1 = bf2f(p[0]), x2 = bf2f(p[64]);
  p[0] = f2bf(x1 * c - x2 * s);
  p[64] = f2bf(x2 * c + x1 * s);
}

// ---------------- MFMA flash attention: one wave per (b, anchor-block, h) ----------------
__global__ __launch_bounds__(256) void k_attn_mfma(
    const unsigned short* __restrict__ qb, const unsigned short* __restrict__ kb,
    const unsigned short* __restrict__ vt, const int* __restrict__ anchors,
    unsigned short* __restrict__ ob) {
  __shared__ __align__(16) unsigned short P_all[4][16 * 40];
  int w = threadIdx.x >> 6, lane = threadIdx.x & 63;
  int blk = blockIdx.x * 4 + w;            // ((b*NA + a)*H + h)
  int h = blk & 15, a = (blk >> 4) & 63, b = blk >> 10;
  int ql = lane & 15, p = lane >> 4;
  int apos = anchors[b * NA_ + a];
  unsigned short* P = P_all[w];

  const unsigned short* qbase = qb + ((size_t)(b * Q_ + a * 16 + ql)) * D_ + h * DH_;
  bf16x8 qf[4];
#pragma unroll
  for (int ks = 0; ks < 4; ++ks)
    qf[ks] = *(const bf16x8*)(qbase + ks * 32 + p * 8);

  const unsigned short* kbb = kb + (size_t)b * KV_ * D_ + h * DH_;
  const unsigned short* vtb = vt + ((size_t)(b * H_ + h)) * 128 * KV_;

  f32x4 o[8];
#pragma unroll
  for (int nt = 0; nt < 8; ++nt) o[nt] = (f32x4){0.f, 0.f, 0.f, 0.f};
  float mrun = -3.0e38f, lrun = 0.f;

  int ncx = (apos + 31) >> 5;
  const float scl = 0.08838834764831845f;

  for (int t = 0; t <= ncx; ++t) {
    int ktb = (t < ncx) ? (t << 5) : (S_ + a * 16);
    int rem = apos - (t << 5);
    int vc = (t < ncx) ? (rem < 32 ? rem : 32) : 16;
    float s[2][4];
#pragma unroll
    for (int g = 0; g < 2; ++g) {
      if (g * 16 < vc) {
        f32x4 accs = (f32x4){0.f, 0.f, 0.f, 0.f};
        const unsigned short* krow = kbb + (size_t)(ktb + g * 16 + ql) * D_;
#pragma unroll
        for (int ks = 0; ks < 4; ++ks) {
          bf16x8 kf = *(const bf16x8*)(krow + ks * 32 + p * 8);
          accs = __builtin_amdgcn_mfma_f32_16x16x32_bf16(kf, qf[ks], accs, 0, 0, 0);
        }
#pragma unroll
        for (int r = 0; r < 4; ++r) {
          int kl = g * 16 + p * 4 + r;
          s[g][r] = (kl < vc) ? accs[r] * scl : -3.0e38f;
        }
      } else {
#pragma unroll
        for (int r = 0; r < 4; ++r) s[g][r] = -3.0e38f;
      }
    }
    float mt = s[0][0];
#pragma unroll
    for (int g = 0; g < 2; ++g)
#pragma unroll
      for (int r = 0; r < 4; ++r) mt = fmaxf(mt, s[g][r]);
    mt = fmaxf(mt, __shfl_xor(mt, 16));
    mt = fmaxf(mt, __shfl_xor(mt, 32));
    float mnew = fmaxf(mrun, mt);
    float corr = __expf(mrun - mnew);
    float psum = 0.f;
#pragma unroll
    for (int g = 0; g < 2; ++g) {
      float p0 = __expf(s[g][0] - mnew), p1 = __expf(s[g][1] - mnew);
      float p2 = __expf(s[g][2] - mnew), p3 = __expf(s[g][3] - mnew);
      psum += p0 + p1 + p2 + p3;
      ushort2 w0, w1;
      w0.x = f2bf(p0); w0.y = f2bf(p1); w1.x = f2bf(p2); w1.y = f2bf(p3);
      int eo = ql * 40 + g * 16 + p * 4;
      *(ushort2*)(P + eo) = w0;
      *(ushort2*)(P + eo + 2) = w1;
    }
    psum += __shfl_xor(psum, 16);
    psum += __shfl_xor(psum, 32);
    lrun = lrun * corr + psum;
    mrun = mnew;
    float cr[4];
#pragma unroll
    for (int r = 0; r < 4; ++r) cr[r] = __shfl(corr, p * 4 + r);
#pragma unroll
    for (int nt = 0; nt < 8; ++nt)
#pragma unroll
      for (int r = 0; r < 4; ++r) o[nt][r] *= cr[r];
    bf16x8 pf = *(const bf16x8*)(P + ql * 40 + p * 8);
#pragma unroll
    for (int nt = 0; nt < 8; ++nt) {
      bf16x8 vf = *(const bf16x8*)(vtb + (size_t)(nt * 16 + ql) * KV_ + ktb + p * 8);
      o[nt] = __builtin_amdgcn_mfma_f32_16x16x32_bf16(pf, vf, o[nt], 0, 0, 0);
    }
  }
  float lq[4];
#pragma unroll
  for (int r = 0; r < 4; ++r) lq[r] = 1.f / __shfl(lrun, p * 4 + r);
  unsigned short* obase = ob + ((size_t)(b * Q_ + a * 16)) * D_ + h * DH_;
#pragma unroll
  for (int nt = 0; nt < 8; ++nt)
#pragma unroll
    for (int r = 0; r < 4; ++r)
      obase[(size_t)(p * 4 + r) * D_ + nt * 16 + ql] = f2bf(o[nt][r] * lq[r]);
}

// ---------------- residual + RMSNorm ----------------
__global__ void k_rmsnorm(const unsigned short* __restrict__ x_kv, const float* __restrict__ proj,
                          const float* __restrict__ nw, unsigned short* __restrict__ outp) {
  int row = blockIdx.x;
  int b = row >> 10, qi = row & 1023;
  const unsigned short* emb = x_kv + ((size_t)b * KV_ + S_ + qi) * D_;
  const float* pr = proj + (size_t)row * D_;
  __shared__ float red[256];
  float h[8];
  float ssum = 0.f;
#pragma unroll
  for (int i = 0; i < 8; ++i) {
    int d = threadIdx.x + i * 256;
    h[i] = bf2f(emb[d]) + pr[d];
    ssum += h[i] * h[i];
  }
  red[threadIdx.x] = ssum;
  __syncthreads();
  for (int s = 128; s; s >>= 1) {
    if (threadIdx.x < s) red[threadIdx.x] += red[threadIdx.x + s];
    __syncthreads();
  }
  float scale = rsqrtf(red[0] / (float)D_ + 1e-6f);
#pragma unroll
  for (int i = 0; i < 8; ++i) {
    int d = threadIdx.x + i * 256;
    outp[(size_t)row * D_ + d] = f2bf(h[i] * scale * nw[d]);
  }
}

// ---------------- combine LM-head partials ----------------
__global__ void k_combine(const float* __restrict__ pm, const float* __restrict__ ps,
                          const int* __restrict__ pbi, const float* __restrict__ plab,
                          const int* __restrict__ labels, float* __restrict__ ts) {
  int t = blockIdx.x * 256 + threadIdx.x;
  if (t >= NTOK_) return;
  const float* pmr = pm + (size_t)t * VTILES_;
  const float* psr = ps + (size_t)t * VTILES_;
  const int* pbir = pbi + (size_t)t * VTILES_;
  const float* plabr = plab + (size_t)t * VTILES_;
  float M = -3.0e38f; int bi = 0;
  for (int x = 0; x < VTILES_; ++x) {
    float v = pmr[x];
    if (v > M) { M = v; bi = pbir[x]; }
  }
  float ssum = 0.f, labl = -3.0e38f;
  for (int x = 0; x < VTILES_; ++x) {
    ssum += psr[x] * __expf(pmr[x] - M);
    labl = fmaxf(labl, plabr[x]);
  }
  float lse = M + logf(ssum);
  int lab = labels[t];
  int off = t & 15;
  float valid = (lab != -100) ? 1.f : 0.f;
  float w = (off == 0) ? 0.f : __expf(-(float)(off - 1) / 7.0f);
  w *= valid;
  float nll = (lab != -100) ? (lse - labl) : 0.f;
  float correct = (valid > 0.f && bi == lab) ? 1.f : 0.f;
  ts[t * 4 + 0] = nll * w;
  ts[t * 4 + 1] = w;
  ts[t * 4 + 2] = correct;
  ts[t * 4 + 3] = valid;
}

// ---------------- final reduction ----------------
__global__ void k_finalize(const float* __restrict__ ts, float* __restrict__ out) {
  __shared__ float r0[256], r1[256], r2[256], r3[256];
  int tid = threadIdx.x;
  float s0 = 0, s1 = 0, s2 = 0, s3 = 0;
  for (int t = tid; t < NTOK_; t += 256) {
    s0 += ts[t * 4 + 0]; s1 += ts[t * 4 + 1];
    s2 += ts[t * 4 + 2]; s3 += ts[t * 4 + 3];
  }
  r0[tid] = s0; r1[tid] = s1; r2[tid] = s2; r3[tid] = s3;
  __syncthreads();
  for (int s = 128; s; s >>= 1) {
    if (tid < s) {
      r0[tid] += r0[tid + s]; r1[tid] += r1[tid + s];
      r2[tid] += r2[tid + s]; r3[tid] += r3[tid + s];
    }
    __syncthreads();
  }
  if (tid == 0) {
    out[0] = r0[0] / fmaxf(r1[0], 1e-6f);
    out[1] = r2[0] / fmaxf(r3[0], 1.f);
  }
}

extern "C" void kernel_launch(void* const* d_in, const int* in_sizes, int n_in,
                              void* d_out, int out_size, void* d_ws, size_t ws_size,
                              hipStream_t stream) {
  const int* input_ids = (const int*)d_in[0];
  const float* hs = (const float*)d_in[1];
  const float* lm_head = (const float*)d_in[3];
  const float* norm_w = (const float*)d_in[4];
  const int* anchors = (const int*)d_in[5];
  const float* ctx_w = (const float*)d_in[6];
  const float* embed = (const float*)d_in[7];
  const float* wq = (const float*)d_in[8];
  const float* wk = (const float*)d_in[9];
  const float* wv = (const float*)d_in[10];
  const float* wo = (const float*)d_in[11];
  float* out = (float*)d_out;

  char* base = (char*)d_ws;
  size_t off = 0;
  unsigned short* x_kv_bf = (unsigned short*)(base + off); off += (size_t)B_ * KV_ * D_ * 2;
  unsigned short* wkb = (unsigned short*)(base + off); off += (size_t)D_ * D_ * 2;
  unsigned short* wvb = (unsigned short*)(base + off); off += (size_t)D_ * D_ * 2;
  unsigned short* wqb = (unsigned short*)(base + off); off += (size_t)D_ * D_ * 2;
  unsigned short* wob = (unsigned short*)(base + off); off += (size_t)D_ * D_ * 2;
  unsigned short* hidden_bf = (unsigned short*)(base + off); off += (size_t)NTOK_ * D_ * 2;
  unsigned short* attn_bf = (unsigned short*)(base + off); off += (size_t)NTOK_ * D_ * 2;
  float* proj = (float*)(base + off); off += (size_t)NTOK_ * D_ * 4;
  float* pm = (float*)(base + off); off += (size_t)NTOK_ * VTILES_ * 4;
  float* psum = (float*)(base + off); off += (size_t)NTOK_ * VTILES_ * 4;
  float* plab = (float*)(base + off); off += (size_t)NTOK_ * VTILES_ * 4;
  int* pbi = (int*)(base + off); off += (size_t)NTOK_ * VTILES_ * 4;
  float* tstats = (float*)(base + off); off += (size_t)NTOK_ * 4 * 4;
  int* dids = (int*)(base + off); off += NTOK_ * 4;
  int* dpos = (int*)(base + off); off += NTOK_ * 4;
  int* labels = (int*)(base + off); off += NTOK_ * 4;
  // REGION A (aliased): [ctxA | ctx_wbf | kbuf | vtbuf | qbuf] later reused as lm_bf
  char* regA = base + off;
  const size_t SLACK = 65536;
  unsigned short* ctxA = (unsigned short*)(regA);                                   // 50.3 MB
  unsigned short* ctx_wbf = (unsigned short*)(regA + 50331648);                     // 25.2 MB
  unsigned short* kbuf = (unsigned short*)(regA + 50331648 + 25165824);             // 25.2 MB + slack
  unsigned short* vtbuf = (unsigned short*)(regA + 50331648 + 2 * 25165824 + SLACK);// 25.2 MB + slack
  unsigned short* qbuf = (unsigned short*)(regA + 50331648 + 3 * 25165824 + 2 * SLACK);
  unsigned short* lm_bf = (unsigned short*)(regA);                                  // 131 MB alias

  k_meta<<<(NTOK_ + 255) / 256, 256, 0, stream>>>(input_ids, anchors, dids, dpos, labels);
  k_cvt<<<((D_ * (L_ * D_) / 4) + 255) / 256, 256, 0, stream>>>(ctx_w, ctx_wbf, D_ * (L_ * D_) / 4);
  k_cvt<<<((D_ * D_ / 4) + 255) / 256, 256, 0, stream>>>(wk, wkb, D_ * D_ / 4);
  k_cvt<<<((D_ * D_ / 4) + 255) / 256, 256, 0, stream>>>(wv, wvb, D_ * D_ / 4);
  k_cvt<<<((D_ * D_ / 4) + 255) / 256, 256, 0, stream>>>(wq, wqb, D_ * D_ / 4);
  k_cvt<<<((D_ * D_ / 4) + 255) / 256, 256, 0, stream>>>(wo, wob, D_ * D_ / 4);
  k_cvt_ctx<<<B_ * S_ * L_, 256, 0, stream>>>(hs, ctxA);
  k_gather<<<NTOK_, 256, 0, stream>>>(embed, dids, x_kv_bf);

  // ctx projection -> x_kv ctx rows
  k_mfma_bt<1, 0><<<(4096 / 128) * (2048 / 128), 256, 0, stream>>>(
      ctxA, ctx_wbf, nullptr, x_kv_bf, 4096, 2048, 6144, 30, 0LL, 11, (long long)Q_ * D_,
      nullptr, nullptr, nullptr, nullptr, nullptr);
  // K
  k_mfma_bt<1, 0><<<(6144 / 128) * (2048 / 128), 256, 0, stream>>>(
      x_kv_bf, wkb, nullptr, kbuf, 6144, 2048, 2048, 30, 0LL, 30, 0LL,
      nullptr, nullptr, nullptr, nullptr, nullptr);
  // V -> transposed store vt[b][h][dim][kv]
  k_mfma_bt<3, 0><<<(6144 / 128) * (2048 / 128), 256, 0, stream>>>(
      x_kv_bf, wvb, nullptr, vtbuf, 6144, 2048, 2048, 30, 0LL, 30, 0LL,
      nullptr, nullptr, nullptr, nullptr, nullptr);
  // Q
  k_mfma_bt<1, 0><<<(2048 / 128) * (2048 / 128), 256, 0, stream>>>(
      x_kv_bf + (size_t)S_ * D_, wqb, nullptr, qbuf, 2048, 2048, 2048, 10,
      (long long)(KV_ - Q_) * D_, 30, 0LL,
      nullptr, nullptr, nullptr, nullptr, nullptr);
  // RoPE
  k_rope<<<(NTOK_ * H_ * 64) / 256, 256, 0, stream>>>(qbuf, dpos, 0);
  k_rope<<<(B_ * KV_ * H_ * 64) / 256, 256, 0, stream>>>(kbuf, dpos, 1);
  // attention (MFMA flash)
  k_attn_mfma<<<(B_ * NA_ * H_) / 4, 256, 0, stream>>>(qbuf, kbuf, vtbuf, anchors, attn_bf);
  // output projection -> f32
  k_mfma_bt<0, 0><<<(2048 / 128) * (2048 / 128), 256, 0, stream>>>(
      attn_bf, wob, proj, nullptr, 2048, 2048, 2048, 30, 0LL, 30, 0LL,
      nullptr, nullptr, nullptr, nullptr, nullptr);
  // residual + RMSNorm
  k_rmsnorm<<<NTOK_, 256, 0, stream>>>(x_kv_bf, proj, norm_w, hidden_bf);
  // LM head convert (aliases REGION A — all dead now)
  k_cvt<<<((VOCAB_ * D_ / 4) + 255) / 256, 256, 0, stream>>>(lm_head, lm_bf, VOCAB_ * D_ / 4);
  // LM head GEMM + fused softmax partials (MAP 1: B-panel locality + XCD chunking)
  k_mfma_bt<2, 1><<<(2048 / 128) * (VOCAB_ / 128), 256, 0, stream>>>(
      hidden_bf, lm_bf, nullptr, nullptr, 2048, VOCAB_, 2048, 30, 0LL, 30, 0LL,
      labels, pm, psum, pbi, plab);
  k_combine<<<(NTOK_ + 255) / 256, 256, 0, stream>>>(pm, psum, pbi, plab, labels, tstats);
  k_finalize<<<1, 256, 0, stream>>>(tstats, out);
}

// Round 5
// 1312.058 us; speedup vs baseline: 7.7853x; 1.0476x over previous
//
#include <hip/hip_runtime.h>

#define B_ 2
#define S_ 2048
#define D_ 2048
#define L_ 3
#define H_ 16
#define DH_ 128
#define BLK_ 16
#define NA_ 64
#define Q_ 1024
#define KV_ 3072
#define VOCAB_ 32000
#define MASK_ID_ 31999
#define NTOK_ (B_*Q_)          // 2048
#define VTILES_ (VOCAB_/128)   // 250
#define NCHUNK_ 4

typedef __attribute__((ext_vector_type(8))) short bf16x8;
typedef __attribute__((ext_vector_type(4))) float f32x4;
typedef const __attribute__((address_space(1))) void* gptr_t;
typedef __attribute__((address_space(3))) void* lptr_t;

__device__ inline unsigned short f2bf(float x) {
  unsigned int u = __float_as_uint(x);
  unsigned int r = (u + 0x7fff + ((u >> 16) & 1)) >> 16;
  return (unsigned short)r;
}
__device__ inline float bf2f(unsigned short u) {
  return __uint_as_float(((unsigned int)u) << 16);
}

// ---------------- meta ----------------
__global__ void k_meta(const int* __restrict__ ids, const int* __restrict__ anchors,
                       int* __restrict__ dids, int* __restrict__ dpos, int* __restrict__ labels) {
  int t = blockIdx.x * 256 + threadIdx.x;
  if (t >= NTOK_) return;
  int b = t >> 10, qi = t & 1023;
  int a = qi >> 4, off = qi & 15;
  int ap = anchors[b * NA_ + a];
  dpos[t] = ap + off;
  dids[t] = (off == 0) ? ids[b * S_ + ap] : MASK_ID_;
  labels[t] = (off == 0) ? -100 : ids[b * S_ + ap + off];
}

// ---------------- f32 -> bf16 convert (n divisible by 4) ----------------
__global__ void k_cvt(const float* __restrict__ in, unsigned short* __restrict__ out, int n4) {
  int i = blockIdx.x * 256 + threadIdx.x;
  if (i >= n4) return;
  float4 v = ((const float4*)in)[i];
  ushort4 o;
  o.x = f2bf(v.x); o.y = f2bf(v.y); o.z = f2bf(v.z); o.w = f2bf(v.w);
  ((ushort4*)out)[i] = o;
}

// ---------------- ctx_cat gather+convert ----------------
__global__ void k_cvt_ctx(const float* __restrict__ hs, unsigned short* __restrict__ out) {
  int bi = blockIdx.x;          // row*3 + l
  int l = bi % 3, row = bi / 3; // row = b*S+s
  const float4* src = (const float4*)(hs + ((size_t)l * B_ * S_ + row) * (size_t)D_);
  ushort4* dst = (ushort4*)(out + (size_t)row * (3 * D_) + (size_t)l * D_);
  for (int i = threadIdx.x; i < D_ / 4; i += 256) {
    float4 v = src[i];
    ushort4 o;
    o.x = f2bf(v.x); o.y = f2bf(v.y); o.z = f2bf(v.z); o.w = f2bf(v.w);
    dst[i] = o;
  }
}

// ---------------- embedding gather -> bf16 draft rows of x_kv ----------------
__global__ void k_gather(const float* __restrict__ table, const int* __restrict__ dids,
                         unsigned short* __restrict__ x_kv) {
  int row = blockIdx.x;                 // 0..NTOK_
  int b = row >> 10, qi = row & 1023;
  const float4* src = (const float4*)(table + (size_t)dids[row] * D_);
  ushort4* dst = (ushort4*)(x_kv + ((size_t)b * KV_ + S_ + qi) * D_);
  for (int i = threadIdx.x; i < D_ / 4; i += 256) {
    float4 v = src[i];
    ushort4 o;
    o.x = f2bf(v.x); o.y = f2bf(v.y); o.z = f2bf(v.z); o.w = f2bf(v.w);
    dst[i] = o;
  }
}

// ---------------- bf16 MFMA GEMM (m97 structure): C[M,N] = A[M,K] @ Bw[N,K]^T ----------------
// CMODE 0: f32 store   CMODE 1: bf16 store   CMODE 2: LM-head partials
// CMODE 3: bf16 V^T store (vt[b][h][dim][kv]), hardcoded for M=B*KV, N=D
// MAP 0: col-tile fastest   MAP 1: row-tile fastest + XCD-chunked swizzle (nwg%8==0)
template <int CMODE, int MAP>
__global__ __launch_bounds__(256) void k_mfma_bt(
    const unsigned short* __restrict__ A, const unsigned short* __restrict__ Bw,
    float* __restrict__ Cf, unsigned short* __restrict__ Cb,
    int M, int N, int K, int adivlog, long long abump, int cdivlog, long long cbump,
    const int* __restrict__ labels, float* __restrict__ pm, float* __restrict__ ps,
    int* __restrict__ pbi, float* __restrict__ plab) {
  __shared__ unsigned short As[128 * 32];
  __shared__ unsigned short Bs[128 * 32];
  int bx, by;
  if (MAP == 0) {
    int ntn = N >> 7;
    bx = blockIdx.x % ntn, by = blockIdx.x / ntn;
  } else {
    int per = gridDim.x >> 3;
    int wgid = (blockIdx.x & 7) * per + (blockIdx.x >> 3);  // bijective: nwg%8==0
    int ntm = M >> 7;
    by = wgid % ntm, bx = wgid / ntm;
  }
  int rowbase = by << 7, colbase = bx << 7;
  int tid = threadIdx.x, lane = tid & 63, w = tid >> 6;
  int wr = w >> 1, wc = w & 1;
  int lo = lane & 15, hi = lane >> 4;

  f32x4 acc[4][4];
#pragma unroll
  for (int m = 0; m < 4; ++m)
#pragma unroll
    for (int n = 0; n < 4; ++n) acc[m][n] = (f32x4){0.f, 0.f, 0.f, 0.f};

  for (int kt = 0; kt < K; kt += 32) {
#pragma unroll
    for (int i = 0; i < 2; ++i) {
      int seg = i * 4 + w;                       // 0..7, wave-uniform
      int rloc = seg * 16 + (lane >> 2);         // row within tile
      int kcol = kt + ((lane & 3) << 3);
      int ra = rowbase + rloc;
      long long aoff = (long long)ra * K + (long long)(ra >> adivlog) * abump + kcol;
      __builtin_amdgcn_global_load_lds((gptr_t)(A + aoff), (lptr_t)(As + seg * 512), 16, 0, 0);
      int rb = colbase + rloc;
      long long boff = (long long)rb * K + kcol;
      __builtin_amdgcn_global_load_lds((gptr_t)(Bw + boff), (lptr_t)(Bs + seg * 512), 16, 0, 0);
    }
    __syncthreads();
    bf16x8 af[4], bfv[4];
#pragma unroll
    for (int m = 0; m < 4; ++m) {
      int row = wr * 64 + m * 16 + lo;
      af[m] = *(const bf16x8*)(As + row * 32 + (hi << 3));
    }
#pragma unroll
    for (int n = 0; n < 4; ++n) {
      int row = wc * 64 + n * 16 + lo;
      bfv[n] = *(const bf16x8*)(Bs + row * 32 + (hi << 3));
    }
#pragma unroll
    for (int m = 0; m < 4; ++m)
#pragma unroll
      for (int n = 0; n < 4; ++n)
        acc[m][n] = __builtin_amdgcn_mfma_f32_16x16x32_bf16(af[m], bfv[n], acc[m][n], 0, 0, 0);
    __syncthreads();
  }

  if (CMODE == 0 || CMODE == 1) {
#pragma unroll
    for (int m = 0; m < 4; ++m)
#pragma unroll
      for (int n = 0; n < 4; ++n)
#pragma unroll
        for (int r4 = 0; r4 < 4; ++r4) {
          int row = rowbase + wr * 64 + m * 16 + hi * 4 + r4;
          int col = colbase + wc * 64 + n * 16 + lo;
          size_t addr = (size_t)row * N + (size_t)(row >> cdivlog) * cbump + col;
          if (CMODE == 0) Cf[addr] = acc[m][n][r4];
          else Cb[addr] = f2bf(acc[m][n][r4]);
        }
  } else if (CMODE == 3) {
    // V^T store: row = b*KV + kv (M=6144), col = h*128 + dim
#pragma unroll
    for (int m = 0; m < 4; ++m)
#pragma unroll
      for (int n = 0; n < 4; ++n)
#pragma unroll
        for (int r4 = 0; r4 < 4; ++r4) {
          int row = rowbase + wr * 64 + m * 16 + hi * 4 + r4;
          int col = colbase + wc * 64 + n * 16 + lo;
          int bb = row >= KV_;
          int kv = row - bb * KV_;
          size_t addr = ((size_t)(bb * H_ + (col >> 7)) * 128 + (col & 127)) * KV_ + kv;
          Cb[addr] = f2bf(acc[m][n][r4]);
        }
  } else {
    // LM-head epilogue
    float* f = (float*)As;
    int* ii = (int*)Bs;
    if (tid < 128) { f[640 + tid] = -3.0e38f; ii[256 + tid] = labels[rowbase + tid]; }
    __syncthreads();
#pragma unroll
    for (int m = 0; m < 4; ++m)
#pragma unroll
      for (int r4 = 0; r4 < 4; ++r4) {
        int trow = wr * 64 + m * 16 + hi * 4 + r4;
        float mx = acc[m][0][r4];
        int arg = colbase + wc * 64 + 0 * 16 + lo;
#pragma unroll
        for (int n = 1; n < 4; ++n) {
          float v = acc[m][n][r4];
          int c = colbase + wc * 64 + n * 16 + lo;
          if (v > mx || (v == mx && c < arg)) { mx = v; arg = c; }
        }
#pragma unroll
        for (int d = 1; d < 16; d <<= 1) {
          float om = __shfl_xor(mx, d);
          int oc = __shfl_xor(arg, d);
          if (om > mx || (om == mx && oc < arg)) { mx = om; arg = oc; }
        }
        if (lo == 0) { f[wc * 128 + trow] = mx; ii[wc * 128 + trow] = arg; }
      }
    __syncthreads();
    if (tid < 128) {
      float a = f[tid], b = f[128 + tid];
      int aa = ii[tid], bb = ii[128 + tid];
      float g; int ga;
      if (b > a || (b == a && bb < aa)) { g = b; ga = bb; } else { g = a; ga = aa; }
      f[512 + tid] = g; ii[384 + tid] = ga;
    }
    __syncthreads();
#pragma unroll
    for (int m = 0; m < 4; ++m)
#pragma unroll
      for (int r4 = 0; r4 < 4; ++r4) {
        int trow = wr * 64 + m * 16 + hi * 4 + r4;
        float gm = f[512 + trow];
        float s = 0.f;
#pragma unroll
        for (int n = 0; n < 4; ++n) s += __expf(acc[m][n][r4] - gm);
#pragma unroll
        for (int d = 1; d < 16; d <<= 1) s += __shfl_xor(s, d);
        if (lo == 0) f[256 + wc * 128 + trow] = s;
        int lab = ii[256 + trow];
        int rel = lab - colbase - wc * 64;
        if (rel >= 0 && rel < 64 && (rel & 15) == lo) {
#pragma unroll
          for (int n = 0; n < 4; ++n)
            if ((rel >> 4) == n) f[640 + trow] = acc[m][n][r4];
        }
      }
    __syncthreads();
    if (tid < 128) {
      int grow = rowbase + tid;
      size_t p = (size_t)grow * VTILES_ + bx;
      pm[p] = f[512 + tid];
      ps[p] = f[256 + tid] + f[256 + 128 + tid];
      pbi[p] = ii[384 + tid];
      plab[p] = f[640 + tid];
    }
  }
}

// ---------------- RoPE in-place on bf16 ----------------
__global__ void k_rope(unsigned short* __restrict__ x, const int* __restrict__ dpos, int mode) {
  int idx = blockIdx.x * 256 + threadIdx.x;
  int j = idx & 63;
  int h = (idx >> 6) & 15;
  int row = idx >> 10;
  int pos;
  if (mode == 0) {
    if (row >= NTOK_) return;
    pos = dpos[row];
  } else {
    if (row >= B_ * KV_) return;
    int b = row / KV_, kvi = row % KV_;
    pos = (kvi < S_) ? kvi : dpos[b * Q_ + (kvi - S_)];
  }
  float inv = expf(-(float)j * (9.210340371976184f / 64.f));
  float ang = (float)pos * inv;
  float c = cosf(ang), s = sinf(ang);
  unsigned short* p = x + (size_t)row * D_ + h * DH_ + j;
  float x1 = bf2f(p[0]), x2 = bf2f(p[64]);
  p[0] = f2bf(x1 * c - x2 * s);
  p[64] = f2bf(x2 * c + x1 * s);
}

// ---------------- MFMA flash attention, 4-way context split ----------------
// One wave per (b, anchor-block, h, chunk). Chunk c covers ctx keys
// [c*512, min(apos,(c+1)*512)); chunk 3 also covers the 16 draft keys.
// Outputs UNNORMALIZED partials (m, l, O) for the combine kernel.
__global__ __launch_bounds__(256) void k_attn_part(
    const unsigned short* __restrict__ qb, const unsigned short* __restrict__ kb,
    const unsigned short* __restrict__ vt, const int* __restrict__ anchors,
    float* __restrict__ pm_att, float* __restrict__ pl_att, float* __restrict__ po_att) {
  __shared__ __align__(16) unsigned short P_all[4][16 * 40];
  int w = threadIdx.x >> 6, lane = threadIdx.x & 63;
  int blk = blockIdx.x * 4 + w;            // (((b*NA + a)*H + h)*4 + chunk)
  int chunk = blk & 3, h = (blk >> 2) & 15, a = (blk >> 6) & 63, b = blk >> 12;
  int ql = lane & 15, p = lane >> 4;
  int apos = anchors[b * NA_ + a];

  int cstart = chunk << 9;
  int cend = min(apos, cstart + 512);
  int len = (cend > cstart) ? (cend - cstart) : 0;
  int ntile = (len + 31) >> 5;
  int total = ntile + ((chunk == 3) ? 1 : 0);

  if (total == 0) {
    if (p == 0) { pm_att[blk * 16 + ql] = -3.0e38f; pl_att[blk * 16 + ql] = 0.f; }
    return;
  }
  unsigned short* P = P_all[w];

  const unsigned short* qbase = qb + ((size_t)(b * Q_ + a * 16 + ql)) * D_ + h * DH_;
  bf16x8 qf[4];
#pragma unroll
  for (int ks = 0; ks < 4; ++ks)
    qf[ks] = *(const bf16x8*)(qbase + ks * 32 + p * 8);

  const unsigned short* kbb = kb + (size_t)b * KV_ * D_ + h * DH_;
  const unsigned short* vtb = vt + ((size_t)(b * H_ + h)) * 128 * KV_;

  f32x4 o[8];
#pragma unroll
  for (int nt = 0; nt < 8; ++nt) o[nt] = (f32x4){0.f, 0.f, 0.f, 0.f};
  float mrun = -3.0e38f, lrun = 0.f;
  const float scl = 0.08838834764831845f;

  for (int t = 0; t < total; ++t) {
    bool isdraft = (chunk == 3) && (t == ntile);
    int ktb = isdraft ? (S_ + a * 16) : (cstart + (t << 5));
    int vc = isdraft ? 16 : min(32, cend - ktb);
    float s[2][4];
#pragma unroll
    for (int g = 0; g < 2; ++g) {
      if (g * 16 < vc) {
        f32x4 accs = (f32x4){0.f, 0.f, 0.f, 0.f};
        const unsigned short* krow = kbb + (size_t)(ktb + g * 16 + ql) * D_;
#pragma unroll
        for (int ks = 0; ks < 4; ++ks) {
          bf16x8 kf = *(const bf16x8*)(krow + ks * 32 + p * 8);
          accs = __builtin_amdgcn_mfma_f32_16x16x32_bf16(kf, qf[ks], accs, 0, 0, 0);
        }
#pragma unroll
        for (int r = 0; r < 4; ++r) {
          int kl = g * 16 + p * 4 + r;
          s[g][r] = (kl < vc) ? accs[r] * scl : -3.0e38f;
        }
      } else {
#pragma unroll
        for (int r = 0; r < 4; ++r) s[g][r] = -3.0e38f;
      }
    }
    float mt = s[0][0];
#pragma unroll
    for (int g = 0; g < 2; ++g)
#pragma unroll
      for (int r = 0; r < 4; ++r) mt = fmaxf(mt, s[g][r]);
    mt = fmaxf(mt, __shfl_xor(mt, 16));
    mt = fmaxf(mt, __shfl_xor(mt, 32));
    float mnew = fmaxf(mrun, mt);
    float corr = __expf(mrun - mnew);
    float psum = 0.f;
#pragma unroll
    for (int g = 0; g < 2; ++g) {
      float p0 = __expf(s[g][0] - mnew), p1 = __expf(s[g][1] - mnew);
      float p2 = __expf(s[g][2] - mnew), p3 = __expf(s[g][3] - mnew);
      psum += p0 + p1 + p2 + p3;
      ushort2 w0, w1;
      w0.x = f2bf(p0); w0.y = f2bf(p1); w1.x = f2bf(p2); w1.y = f2bf(p3);
      int eo = ql * 40 + g * 16 + p * 4;
      *(ushort2*)(P + eo) = w0;
      *(ushort2*)(P + eo + 2) = w1;
    }
    psum += __shfl_xor(psum, 16);
    psum += __shfl_xor(psum, 32);
    lrun = lrun * corr + psum;
    mrun = mnew;
    float cr[4];
#pragma unroll
    for (int r = 0; r < 4; ++r) cr[r] = __shfl(corr, p * 4 + r);
#pragma unroll
    for (int nt = 0; nt < 8; ++nt)
#pragma unroll
      for (int r = 0; r < 4; ++r) o[nt][r] *= cr[r];
    bf16x8 pf = *(const bf16x8*)(P + ql * 40 + p * 8);
#pragma unroll
    for (int nt = 0; nt < 8; ++nt) {
      bf16x8 vf = *(const bf16x8*)(vtb + (size_t)(nt * 16 + ql) * KV_ + ktb + p * 8);
      o[nt] = __builtin_amdgcn_mfma_f32_16x16x32_bf16(pf, vf, o[nt], 0, 0, 0);
    }
  }
  if (p == 0) { pm_att[blk * 16 + ql] = mrun; pl_att[blk * 16 + ql] = lrun; }
  float* pob = po_att + (size_t)blk * 2048;
#pragma unroll
  for (int nt = 0; nt < 8; ++nt)
#pragma unroll
    for (int r = 0; r < 4; ++r)
      pob[(p * 4 + r) * 128 + nt * 16 + ql] = o[nt][r];
}

// ---------------- combine attention partials -> bf16 output ----------------
__global__ __launch_bounds__(256) void k_attn_combine(
    const float* __restrict__ pm_att, const float* __restrict__ pl_att,
    const float* __restrict__ po_att, unsigned short* __restrict__ ob) {
  int base = blockIdx.x;            // (b*NA+a)*H + h
  int h = base & 15, a = (base >> 4) & 63, b = base >> 10;
  int d = threadIdx.x & 127, qh = threadIdx.x >> 7;
  int pbase = base * 4;
#pragma unroll
  for (int qq = 0; qq < 8; ++qq) {
    int q = qh * 8 + qq;
    float m0 = pm_att[(pbase + 0) * 16 + q], m1 = pm_att[(pbase + 1) * 16 + q];
    float m2 = pm_att[(pbase + 2) * 16 + q], m3 = pm_att[(pbase + 3) * 16 + q];
    float mg = fmaxf(fmaxf(m0, m1), fmaxf(m2, m3));
    float w0 = __expf(m0 - mg), w1 = __expf(m1 - mg);
    float w2 = __expf(m2 - mg), w3 = __expf(m3 - mg);
    float lg = pl_att[(pbase + 0) * 16 + q] * w0 + pl_att[(pbase + 1) * 16 + q] * w1 +
               pl_att[(pbase + 2) * 16 + q] * w2 + pl_att[(pbase + 3) * 16 + q] * w3;
    float od = po_att[(size_t)(pbase + 0) * 2048 + q * 128 + d] * w0 +
               po_att[(size_t)(pbase + 1) * 2048 + q * 128 + d] * w1 +
               po_att[(size_t)(pbase + 2) * 2048 + q * 128 + d] * w2 +
               po_att[(size_t)(pbase + 3) * 2048 + q * 128 + d] * w3;
    ob[((size_t)(b * Q_ + a * 16 + q)) * D_ + h * DH_ + d] = f2bf(od / lg);
  }
}

// ---------------- residual + RMSNorm ----------------
__global__ void k_rmsnorm(const unsigned short* __restrict__ x_kv, const float* __restrict__ proj,
                          const float* __restrict__ nw, unsigned short* __restrict__ outp) {
  int row = blockIdx.x;
  int b = row >> 10, qi = row & 1023;
  const unsigned short* emb = x_kv + ((size_t)b * KV_ + S_ + qi) * D_;
  const float* pr = proj + (size_t)row * D_;
  __shared__ float red[256];
  float h[8];
  float ssum = 0.f;
#pragma unroll
  for (int i = 0; i < 8; ++i) {
    int d = threadIdx.x + i * 256;
    h[i] = bf2f(emb[d]) + pr[d];
    ssum += h[i] * h[i];
  }
  red[threadIdx.x] = ssum;
  __syncthreads();
  for (int s = 128; s; s >>= 1) {
    if (threadIdx.x < s) red[threadIdx.x] += red[threadIdx.x + s];
    __syncthreads();
  }
  float scale = rsqrtf(red[0] / (float)D_ + 1e-6f);
#pragma unroll
  for (int i = 0; i < 8; ++i) {
    int d = threadIdx.x + i * 256;
    outp[(size_t)row * D_ + d] = f2bf(h[i] * scale * nw[d]);
  }
}

// ---------------- combine LM-head partials ----------------
__global__ void k_combine(const float* __restrict__ pm, const float* __restrict__ ps,
                          const int* __restrict__ pbi, const float* __restrict__ plab,
                          const int* __restrict__ labels, float* __restrict__ ts) {
  int t = blockIdx.x * 256 + threadIdx.x;
  if (t >= NTOK_) return;
  const float* pmr = pm + (size_t)t * VTILES_;
  const float* psr = ps + (size_t)t * VTILES_;
  const int* pbir = pbi + (size_t)t * VTILES_;
  const float* plabr = plab + (size_t)t * VTILES_;
  float M = -3.0e38f; int bi = 0;
  for (int x = 0; x < VTILES_; ++x) {
    float v = pmr[x];
    if (v > M) { M = v; bi = pbir[x]; }
  }
  float ssum = 0.f, labl = -3.0e38f;
  for (int x = 0; x < VTILES_; ++x) {
    ssum += psr[x] * __expf(pmr[x] - M);
    labl = fmaxf(labl, plabr[x]);
  }
  float lse = M + logf(ssum);
  int lab = labels[t];
  int off = t & 15;
  float valid = (lab != -100) ? 1.f : 0.f;
  float w = (off == 0) ? 0.f : __expf(-(float)(off - 1) / 7.0f);
  w *= valid;
  float nll = (lab != -100) ? (lse - labl) : 0.f;
  float correct = (valid > 0.f && bi == lab) ? 1.f : 0.f;
  ts[t * 4 + 0] = nll * w;
  ts[t * 4 + 1] = w;
  ts[t * 4 + 2] = correct;
  ts[t * 4 + 3] = valid;
}

// ---------------- final reduction ----------------
__global__ void k_finalize(const float* __restrict__ ts, float* __restrict__ out) {
  __shared__ float r0[256], r1[256], r2[256], r3[256];
  int tid = threadIdx.x;
  float s0 = 0, s1 = 0, s2 = 0, s3 = 0;
  for (int t = tid; t < NTOK_; t += 256) {
    s0 += ts[t * 4 + 0]; s1 += ts[t * 4 + 1];
    s2 += ts[t * 4 + 2]; s3 += ts[t * 4 + 3];
  }
  r0[tid] = s0; r1[tid] = s1; r2[tid] = s2; r3[tid] = s3;
  __syncthreads();
  for (int s = 128; s; s >>= 1) {
    if (tid < s) {
      r0[tid] += r0[tid + s]; r1[tid] += r1[tid + s];
      r2[tid] += r2[tid + s]; r3[tid] += r3[tid + s];
    }
    __syncthreads();
  }
  if (tid == 0) {
    out[0] = r0[0] / fmaxf(r1[0], 1e-6f);
    out[1] = r2[0] / fmaxf(r3[0], 1.f);
  }
}

extern "C" void kernel_launch(void* const* d_in, const int* in_sizes, int n_in,
                              void* d_out, int out_size, void* d_ws, size_t ws_size,
                              hipStream_t stream) {
  const int* input_ids = (const int*)d_in[0];
  const float* hs = (const float*)d_in[1];
  const float* lm_head = (const float*)d_in[3];
  const float* norm_w = (const float*)d_in[4];
  const int* anchors = (const int*)d_in[5];
  const float* ctx_w = (const float*)d_in[6];
  const float* embed = (const float*)d_in[7];
  const float* wq = (const float*)d_in[8];
  const float* wk = (const float*)d_in[9];
  const float* wv = (const float*)d_in[10];
  const float* wo = (const float*)d_in[11];
  float* out = (float*)d_out;

  char* base = (char*)d_ws;
  size_t off = 0;
  unsigned short* x_kv_bf = (unsigned short*)(base + off); off += (size_t)B_ * KV_ * D_ * 2;
  unsigned short* wkb = (unsigned short*)(base + off); off += (size_t)D_ * D_ * 2;
  unsigned short* wvb = (unsigned short*)(base + off); off += (size_t)D_ * D_ * 2;
  unsigned short* wqb = (unsigned short*)(base + off); off += (size_t)D_ * D_ * 2;
  unsigned short* wob = (unsigned short*)(base + off); off += (size_t)D_ * D_ * 2;
  unsigned short* hidden_bf = (unsigned short*)(base + off); off += (size_t)NTOK_ * D_ * 2;
  unsigned short* attn_bf = (unsigned short*)(base + off); off += (size_t)NTOK_ * D_ * 2;
  float* proj = (float*)(base + off); off += (size_t)NTOK_ * D_ * 4;
  float* pm = (float*)(base + off); off += (size_t)NTOK_ * VTILES_ * 4;
  float* psum = (float*)(base + off); off += (size_t)NTOK_ * VTILES_ * 4;
  float* plab = (float*)(base + off); off += (size_t)NTOK_ * VTILES_ * 4;
  int* pbi = (int*)(base + off); off += (size_t)NTOK_ * VTILES_ * 4;
  float* tstats = (float*)(base + off); off += (size_t)NTOK_ * 4 * 4;
  int* dids = (int*)(base + off); off += NTOK_ * 4;
  int* dpos = (int*)(base + off); off += NTOK_ * 4;
  int* labels = (int*)(base + off); off += NTOK_ * 4;
  // REGION A (aliased): [ctxA | ctx_wbf | kbuf | vtbuf | qbuf], later reused as lm_bf.
  // During attention, ctxA/ctx_wbf (first 75.5 MB) are dead -> attention partials live there.
  char* regA = base + off;
  const size_t SLACK = 65536;
  unsigned short* ctxA = (unsigned short*)(regA);                                   // 50.3 MB
  unsigned short* ctx_wbf = (unsigned short*)(regA + 50331648);                     // 25.2 MB
  unsigned short* kbuf = (unsigned short*)(regA + 50331648 + 25165824);             // 25.2 MB + slack
  unsigned short* vtbuf = (unsigned short*)(regA + 50331648 + 2 * 25165824 + SLACK);// 25.2 MB + slack
  unsigned short* qbuf = (unsigned short*)(regA + 50331648 + 3 * 25165824 + 2 * SLACK);
  unsigned short* lm_bf = (unsigned short*)(regA);                                  // 131 MB alias
  float* po_att = (float*)(regA);                                                   // 67.1 MB (dead ctxA area)
  float* pm_att = (float*)(regA + 67108864);                                        // 0.5 MB
  float* pl_att = (float*)(regA + 67108864 + 524288);                               // 0.5 MB

  k_meta<<<(NTOK_ + 255) / 256, 256, 0, stream>>>(input_ids, anchors, dids, dpos, labels);
  k_cvt<<<((D_ * (L_ * D_) / 4) + 255) / 256, 256, 0, stream>>>(ctx_w, ctx_wbf, D_ * (L_ * D_) / 4);
  k_cvt<<<((D_ * D_ / 4) + 255) / 256, 256, 0, stream>>>(wk, wkb, D_ * D_ / 4);
  k_cvt<<<((D_ * D_ / 4) + 255) / 256, 256, 0, stream>>>(wv, wvb, D_ * D_ / 4);
  k_cvt<<<((D_ * D_ / 4) + 255) / 256, 256, 0, stream>>>(wq, wqb, D_ * D_ / 4);
  k_cvt<<<((D_ * D_ / 4) + 255) / 256, 256, 0, stream>>>(wo, wob, D_ * D_ / 4);
  k_cvt_ctx<<<B_ * S_ * L_, 256, 0, stream>>>(hs, ctxA);
  k_gather<<<NTOK_, 256, 0, stream>>>(embed, dids, x_kv_bf);

  // ctx projection -> x_kv ctx rows
  k_mfma_bt<1, 0><<<(4096 / 128) * (2048 / 128), 256, 0, stream>>>(
      ctxA, ctx_wbf, nullptr, x_kv_bf, 4096, 2048, 6144, 30, 0LL, 11, (long long)Q_ * D_,
      nullptr, nullptr, nullptr, nullptr, nullptr);
  // K
  k_mfma_bt<1, 0><<<(6144 / 128) * (2048 / 128), 256, 0, stream>>>(
      x_kv_bf, wkb, nullptr, kbuf, 6144, 2048, 2048, 30, 0LL, 30, 0LL,
      nullptr, nullptr, nullptr, nullptr, nullptr);
  // V -> transposed store vt[b][h][dim][kv]
  k_mfma_bt<3, 0><<<(6144 / 128) * (2048 / 128), 256, 0, stream>>>(
      x_kv_bf, wvb, nullptr, vtbuf, 6144, 2048, 2048, 30, 0LL, 30, 0LL,
      nullptr, nullptr, nullptr, nullptr, nullptr);
  // Q
  k_mfma_bt<1, 0><<<(2048 / 128) * (2048 / 128), 256, 0, stream>>>(
      x_kv_bf + (size_t)S_ * D_, wqb, nullptr, qbuf, 2048, 2048, 2048, 10,
      (long long)(KV_ - Q_) * D_, 30, 0LL,
      nullptr, nullptr, nullptr, nullptr, nullptr);
  // RoPE
  k_rope<<<(NTOK_ * H_ * 64) / 256, 256, 0, stream>>>(qbuf, dpos, 0);
  k_rope<<<(B_ * KV_ * H_ * 64) / 256, 256, 0, stream>>>(kbuf, dpos, 1);
  // attention: 4-way context split + combine
  k_attn_part<<<(B_ * NA_ * H_ * NCHUNK_) / 4, 256, 0, stream>>>(
      qbuf, kbuf, vtbuf, anchors, pm_att, pl_att, po_att);
  k_attn_combine<<<B_ * NA_ * H_, 256, 0, stream>>>(pm_att, pl_att, po_att, attn_bf);
  // output projection -> f32
  k_mfma_bt<0, 0><<<(2048 / 128) * (2048 / 128), 256, 0, stream>>>(
      attn_bf, wob, proj, nullptr, 2048, 2048, 2048, 30, 0LL, 30, 0LL,
      nullptr, nullptr, nullptr, nullptr, nullptr);
  // residual + RMSNorm
  k_rmsnorm<<<NTOK_, 256, 0, stream>>>(x_kv_bf, proj, norm_w, hidden_bf);
  // LM head convert (aliases REGION A — attention partials dead now)
  k_cvt<<<((VOCAB_ * D_ / 4) + 255) / 256, 256, 0, stream>>>(lm_head, lm_bf, VOCAB_ * D_ / 4);
  // LM head GEMM + fused softmax partials (MAP 1: B-panel locality + XCD chunking)
  k_mfma_bt<2, 1><<<(2048 / 128) * (VOCAB_ / 128), 256, 0, stream>>>(
      hidden_bf, lm_bf, nullptr, nullptr, 2048, VOCAB_, 2048, 30, 0LL, 30, 0LL,
      labels, pm, psum, pbi, plab);
  k_combine<<<(NTOK_ + 255) / 256, 256, 0, stream>>>(pm, psum, pbi, plab, labels, tstats);
  k_finalize<<<1, 256, 0, stream>>>(tstats, out);
}